// Round 2
// baseline (3827.903 us; speedup 1.0000x reference)
//
#include <hip/hip_runtime.h>

#define BN 40000
#define TT 12
#define EE 160000

__device__ __forceinline__ float lrelu(float v){ return v > 0.f ? v : 0.2f*v; }

// ---------------- graph preprocessing ----------------
__global__ void k_hist(const int* __restrict__ ei, int* __restrict__ degcnt, int* __restrict__ cnt){
  int e = blockIdx.x*256 + threadIdx.x;
  if (e < EE){
    atomicAdd(&degcnt[ei[e]], 1);      // src out-degree (ChebConv norm)
    atomicAdd(&cnt[ei[EE + e]], 1);    // dst in-degree (CSR)
  }
}

__global__ void k_dis(const int* __restrict__ degcnt, float* __restrict__ dis){
  int i = blockIdx.x*256 + threadIdx.x;
  if (i < BN){ int d = degcnt[i]; dis[i] = d > 0 ? rsqrtf((float)d) : 0.f; }
}

__global__ void k_scan(const int* __restrict__ cnt, int* __restrict__ rowptr, int* __restrict__ cursor){
  __shared__ int part[1024];
  int tid = threadIdx.x;
  const int CH = 40;                   // 1024*40 >= 40000
  int base = tid*CH;
  int s = 0;
  for (int j=0;j<CH;++j){ int idx=base+j; if (idx<BN) s += cnt[idx]; }
  part[tid] = s; __syncthreads();
  for (int off=1; off<1024; off<<=1){
    int v = (tid>=off)? part[tid-off] : 0;
    __syncthreads();
    part[tid] += v;
    __syncthreads();
  }
  int run = part[tid] - s;             // exclusive base
  for (int j=0;j<CH;++j){ int idx=base+j; if (idx<BN){ rowptr[idx]=run; cursor[idx]=run; run += cnt[idx]; } }
  if (tid==1023) rowptr[BN] = part[1023];
}

__global__ void k_scatter(const int* __restrict__ ei, const float* __restrict__ dis,
                          int* __restrict__ cursor, int* __restrict__ esrc, float* __restrict__ ew){
  int e = blockIdx.x*256 + threadIdx.x;
  if (e < EE){
    int s = ei[e], d = ei[EE+e];
    int p = atomicAdd(&cursor[d], 1);
    esrc[p] = s;
    ew[p] = -dis[s]*dis[d];
  }
}

// ---------------- Cheb propagation (FIN=1 scalars) ----------------
__global__ void k_prop1(const float* __restrict__ x, const int* __restrict__ rowptr,
                        const int* __restrict__ esrc, const float* __restrict__ ew,
                        float* __restrict__ tx1){
  int i = blockIdx.x*256 + threadIdx.x;
  if (i >= BN*TT) return;
  int d = i/TT, t = i - d*TT;
  int r0 = rowptr[d], r1 = rowptr[d+1];
  float a = 0.f;
  for (int p=r0;p<r1;++p) a += ew[p]*x[esrc[p]*TT + t];
  tx1[i] = a;
}

__global__ void k_prop2(const float* __restrict__ x, const float* __restrict__ tx1,
                        const int* __restrict__ rowptr, const int* __restrict__ esrc,
                        const float* __restrict__ ew, float* __restrict__ tx2){
  int i = blockIdx.x*256 + threadIdx.x;
  if (i >= BN*TT) return;
  int d = i/TT, t = i - d*TT;
  int r0 = rowptr[d], r1 = rowptr[d+1];
  float a = 0.f;
  for (int p=r0;p<r1;++p) a += ew[p]*tx1[esrc[p]*TT + t];
  tx2[i] = 2.f*a - x[i];
}

// ---------------- fold cheb_w/cheb_b through gat_w / att vectors ----------------
// gwbuf layout: [k*128+hc] k<3 (384) | gc 384..511 | ask 512+k*2+h | adk 518+k*2+h | asc 524+h | adc 526+h
__global__ void k_precomp(const float* __restrict__ cheb_w, const float* __restrict__ cheb_b,
                          const float* __restrict__ gat_w, const float* __restrict__ att_src,
                          const float* __restrict__ att_dst, float* __restrict__ gwbuf){
  __shared__ float sgw[384]; __shared__ float sgc[128];
  int hc = threadIdx.x; // 128 threads
  for (int k=0;k<3;++k){
    float a=0; for (int c=0;c<64;++c) a += cheb_w[k*64+c]*gat_w[hc*64+c];
    sgw[k*128+hc]=a; gwbuf[k*128+hc]=a;
  }
  { float g=0; for (int c=0;c<64;++c) g += cheb_b[c]*gat_w[hc*64+c]; sgc[hc]=g; gwbuf[384+hc]=g; }
  __syncthreads();
  if (hc<6){ int k=hc>>1, h=hc&1; float a=0,d=0;
    for (int c=0;c<64;++c){ float g=sgw[k*128+h*64+c]; a+=g*att_src[h*64+c]; d+=g*att_dst[h*64+c]; }
    gwbuf[512+hc]=a; gwbuf[518+hc]=d; }
  if (hc<2){ float a=0,d=0;
    for (int c=0;c<64;++c){ float g=sgc[hc*64+c]; a+=g*att_src[hc*64+c]; d+=g*att_dst[hc*64+c]; }
    gwbuf[524+hc]=a; gwbuf[526+hc]=d; }
}

// ---------------- GAT: one wave per (node,t), lane = feature ----------------
__global__ __launch_bounds__(256) void k_gat(const float* __restrict__ x, const float* __restrict__ tx1,
     const float* __restrict__ tx2, const int* __restrict__ rowptr, const int* __restrict__ esrc,
     const float* __restrict__ gwbuf, const float* __restrict__ gat_b, float* __restrict__ sp){
  int wave = (blockIdx.x<<2) + (threadIdx.x>>6);
  int lane = threadIdx.x & 63;
  int d = wave/TT, t = wave - d*TT;

  float ga0 = gwbuf[lane],      ga1 = gwbuf[128+lane], ga2 = gwbuf[256+lane], gac = gwbuf[384+lane];
  float gb0 = gwbuf[64+lane],   gb1 = gwbuf[192+lane], gb2 = gwbuf[320+lane], gbc = gwbuf[448+lane];
  float as00=gwbuf[512], as01=gwbuf[513], as10=gwbuf[514], as11=gwbuf[515], as20=gwbuf[516], as21=gwbuf[517];
  float ad00=gwbuf[518], ad01=gwbuf[519], ad10=gwbuf[520], ad11=gwbuf[521], ad20=gwbuf[522], ad21=gwbuf[523];
  float asc0=gwbuf[524], asc1=gwbuf[525], adc0=gwbuf[526], adc1=gwbuf[527];

  int r0 = rowptr[d], r1 = rowptr[d+1];
  float td0 = x[d*TT+t], td1 = tx1[d*TT+t], td2 = tx2[d*TT+t];
  float adh0 = td0*ad00 + td1*ad10 + td2*ad20 + adc0;
  float adh1 = td0*ad01 + td1*ad11 + td2*ad21 + adc1;
  float es0 = lrelu(td0*as00 + td1*as10 + td2*as20 + asc0 + adh0);   // self loop
  float es1 = lrelu(td0*as01 + td1*as11 + td2*as21 + asc1 + adh1);
  float m0 = es0, m1 = es1;
  for (int p=r0;p<r1;++p){
    int s = esrc[p];
    float s0 = x[s*TT+t], s1 = tx1[s*TT+t], s2 = tx2[s*TT+t];
    m0 = fmaxf(m0, lrelu(s0*as00 + s1*as10 + s2*as20 + asc0 + adh0));
    m1 = fmaxf(m1, lrelu(s0*as01 + s1*as11 + s2*as21 + asc1 + adh1));
  }
  float z0, z1, acc0, acc1;
  { float p0 = __expf(es0 - m0), p1 = __expf(es1 - m1);
    z0 = p0; z1 = p1;
    acc0 = p0*(td0*ga0 + td1*ga1 + td2*ga2 + gac);
    acc1 = p1*(td0*gb0 + td1*gb1 + td2*gb2 + gbc); }
  for (int p=r0;p<r1;++p){
    int s = esrc[p];
    float s0 = x[s*TT+t], s1 = tx1[s*TT+t], s2 = tx2[s*TT+t];
    float e0 = lrelu(s0*as00 + s1*as10 + s2*as20 + asc0 + adh0);
    float e1 = lrelu(s0*as01 + s1*as11 + s2*as21 + asc1 + adh1);
    float p0 = __expf(e0 - m0), p1 = __expf(e1 - m1);
    z0 += p0; z1 += p1;
    acc0 += p0*(s0*ga0 + s1*ga1 + s2*ga2 + gac);
    acc1 += p1*(s0*gb0 + s1*gb1 + s2*gb2 + gbc);
  }
  sp[wave*64 + lane] = 0.5f*(acc0/z0 + acc1/z1) + gat_b[lane];
}

// ---------------- fused temporal pipeline helpers ----------------
__device__ __forceinline__ void conv_tap(const float a[12], float w0, float w1, float w2, float acc[12]){
  #pragma unroll
  for (int t=0;t<12;++t) acc[t] += a[t]*w1;
  #pragma unroll
  for (int t=1;t<12;++t) acc[t] += a[t-1]*w0;
  #pragma unroll
  for (int t=0;t<11;++t) acc[t] += a[t+1]*w2;
}

// processes 8 local columns starting at cl0 of a 32-wide chunk starting at global col cbase
__device__ __forceinline__ void conv_chunk(float (* __restrict__ s_in)[64], const float* __restrict__ wl,
                                           int cl0, int cbase, float acc[12]){
  for (int cb=0; cb<8; cb+=4){
    int cl = cl0 + cb;
    float a0[12],a1[12],a2[12],a3[12];
    #pragma unroll
    for (int t=0;t<12;++t){
      float4 v = *(const float4*)&s_in[t][cbase + cl];
      a0[t]=v.x; a1[t]=v.y; a2[t]=v.z; a3[t]=v.w;
    }
    conv_tap(a0, wl[(cl+0)*3+0], wl[(cl+0)*3+1], wl[(cl+0)*3+2], acc);
    conv_tap(a1, wl[(cl+1)*3+0], wl[(cl+1)*3+1], wl[(cl+1)*3+2], acc);
    conv_tap(a2, wl[(cl+2)*3+0], wl[(cl+2)*3+1], wl[(cl+2)*3+2], acc);
    conv_tap(a3, wl[(cl+3)*3+0], wl[(cl+3)*3+1], wl[(cl+3)*3+2], acc);
  }
}

__device__ __forceinline__ void qkv_chunk(float (* __restrict__ s_in)[64], const float* __restrict__ wb,
                                          int j, int kbase, float acc[12]){
  for (int kb=0; kb<32; kb+=4){
    float a0[12],a1[12],a2[12],a3[12];
    #pragma unroll
    for (int t=0;t<12;++t){
      float4 v = *(const float4*)&s_in[t][kbase + kb];
      a0[t]=v.x; a1[t]=v.y; a2[t]=v.z; a3[t]=v.w;
    }
    float w0 = wb[(kb+0)*193 + j], w1 = wb[(kb+1)*193 + j];
    float w2 = wb[(kb+2)*193 + j], w3 = wb[(kb+3)*193 + j];
    #pragma unroll
    for (int t=0;t<12;++t) acc[t] += a0[t]*w0 + a1[t]*w1 + a2[t]*w2 + a3[t]*w3;
  }
}

// ---------------- fused temporal: tc conv -> MHA -> residual+LN -> bc/fc convs ----------------
__global__ __launch_bounds__(256) void k_temporal(
  const float* __restrict__ sp, const float* __restrict__ x,
  const float* __restrict__ tc_w, const float* __restrict__ tc_b,
  const float* __restrict__ in_w, const float* __restrict__ in_b,
  const float* __restrict__ out_w, const float* __restrict__ out_b,
  const float* __restrict__ res_w, const float* __restrict__ res_b,
  const float* __restrict__ ln_g, const float* __restrict__ ln_b,
  const float* __restrict__ bc_w, const float* __restrict__ bc_b,
  const float* __restrict__ fc_w, const float* __restrict__ fc_b,
  float* __restrict__ out)
{
  __shared__ __align__(16) float wbuf[6208];      // padded weight stage
  __shared__ __align__(16) float s_a[12][64];     // sp, later attention output o
  __shared__ __align__(16) float s_b[12][64];     // tc, later bc accumulator
  __shared__ __align__(16) float s_r[12][64];     // LN result
  __shared__ __align__(16) float s_qkv[12*193];   // qkv (padded), later fc accumulator
  __shared__ float s_red1[12][16], s_red2[12][16];
  __shared__ float s_mu[12], s_iv[12];

  const int nd = blockIdx.x;
  const int tid = threadIdx.x;
  const int o = tid & 63, cq = tid >> 6;

  // P0: load sp row, stage tc_w chunk0 ([o][97], cd=c*3+dt, c<32), init s_b = tc_b
  for (int i=tid;i<768;i+=256) s_a[0][i] = sp[nd*768 + i];
  for (int i=tid;i<6144;i+=256){ int oo=i/96, cd=i%96; wbuf[oo*97+cd] = tc_w[oo*192+cd]; }
  for (int i=tid;i<768;i+=256) s_b[0][i] = tc_b[i&63];
  __syncthreads();

  float acc[12];
  #pragma unroll
  for (int t=0;t<12;++t) acc[t]=0.f;
  conv_chunk(s_a, &wbuf[o*97], cq*8, 0, acc);
  __syncthreads();
  for (int i=tid;i<6144;i+=256){ int oo=i/96, cd=i%96; wbuf[oo*97+cd] = tc_w[oo*192+96+cd]; }
  __syncthreads();
  conv_chunk(s_a, &wbuf[o*97], cq*8, 32, acc);
  #pragma unroll
  for (int t=0;t<12;++t) atomicAdd(&s_b[t][o], acc[t]);
  __syncthreads();

  // QKV: wbuf[k][193], k-chunks of 32
  for (int i=tid;i<6144;i+=256){ int j=i/32, k=i%32; wbuf[k*193+j] = in_w[j*64+k]; }
  __syncthreads();
  float qacc[12];
  if (tid < 192){
    #pragma unroll
    for (int t=0;t<12;++t) qacc[t] = in_b[tid];
    qkv_chunk(s_b, wbuf, tid, 0, qacc);
  }
  __syncthreads();
  for (int i=tid;i<6144;i+=256){ int j=i/32, k=i%32; wbuf[k*193+j] = in_w[j*64+32+k]; }
  __syncthreads();
  if (tid < 192){
    qkv_chunk(s_b, wbuf, tid, 32, qacc);
    #pragma unroll
    for (int t=0;t<12;++t) s_qkv[t*193+tid] = qacc[t];
  }
  __syncthreads();

  // stage out_w [k][65] + attention (NH=4, dh=16, T=12)
  for (int i=tid;i<4096;i+=256){ int oo=i/64, k=i%64; wbuf[k*65+oo] = out_w[i]; }
  if (tid < 48){
    int q = tid>>2, h = tid&3, hb = h*16;
    float qv[16];
    #pragma unroll
    for (int dd=0; dd<16; ++dd) qv[dd] = s_qkv[q*193 + hb + dd];
    float scv[12]; float mx = -1e30f;
    #pragma unroll
    for (int k2=0;k2<12;++k2){
      float s=0;
      #pragma unroll
      for (int dd=0;dd<16;++dd) s += qv[dd]*s_qkv[k2*193 + 64 + hb + dd];
      s *= 0.25f;
      scv[k2]=s; mx=fmaxf(mx,s);
    }
    float z=0;
    #pragma unroll
    for (int k2=0;k2<12;++k2){ float p=__expf(scv[k2]-mx); scv[k2]=p; z+=p; }
    float inv = 1.f/z;
    #pragma unroll
    for (int dd=0;dd<16;++dd){
      float a=0;
      #pragma unroll
      for (int k2=0;k2<12;++k2) a += scv[k2]*s_qkv[k2*193 + 128 + hb + dd];
      s_a[q][hb+dd] = a*inv;          // s_o aliased onto s_a
    }
  }
  __syncthreads();

  // out proj + residual + relu -> s_r (raw)
  for (int r=0;r<3;++r){
    int idx = tid + (r<<8); int t = idx>>6, oo = idx&63;
    float a = out_b[oo];
    for (int kb=0;kb<64;kb+=4){
      float4 v = *(const float4*)&s_a[t][kb];
      a += v.x*wbuf[(kb+0)*65+oo] + v.y*wbuf[(kb+1)*65+oo]
         + v.z*wbuf[(kb+2)*65+oo] + v.w*wbuf[(kb+3)*65+oo];
    }
    float zr = a + x[nd*12+t]*res_w[oo] + res_b[oo];
    s_r[t][oo] = zr > 0.f ? zr : 0.f;
  }
  __syncthreads();

  // LayerNorm over features
  if (tid < 192){
    int t = tid>>4, g = tid&15;
    float4 v = *(const float4*)&s_r[t][g*4];
    s_red1[t][g] = v.x+v.y+v.z+v.w;
    s_red2[t][g] = v.x*v.x+v.y*v.y+v.z*v.z+v.w*v.w;
  }
  __syncthreads();
  if (tid < 12){
    float s=0,q=0;
    #pragma unroll
    for (int g=0;g<16;++g){ s+=s_red1[tid][g]; q+=s_red2[tid][g]; }
    float mu = s*(1.f/64.f), var = q*(1.f/64.f) - mu*mu;
    s_mu[tid]=mu; s_iv[tid]=rsqrtf(fmaxf(var,0.f)+1e-5f);
  }
  __syncthreads();
  // normalize s_r in place + stage bc chunk0 + init s_b = bc_b
  for (int r=0;r<3;++r){
    int idx = tid + (r<<8); int t = idx>>6, oo = idx&63;
    s_r[t][oo] = (s_r[t][oo]-s_mu[t])*s_iv[t]*ln_g[oo] + ln_b[oo];
  }
  for (int i=tid;i<6144;i+=256){ int oo=i/96, cd=i%96; wbuf[oo*97+cd] = bc_w[oo*192+cd]; }
  for (int i=tid;i<768;i+=256) s_b[0][i] = bc_b[i&63];
  __syncthreads();

  // backcast conv
  #pragma unroll
  for (int t=0;t<12;++t) acc[t]=0.f;
  conv_chunk(s_r, &wbuf[o*97], cq*8, 0, acc);
  __syncthreads();
  for (int i=tid;i<6144;i+=256){ int oo=i/96, cd=i%96; wbuf[oo*97+cd] = bc_w[oo*192+96+cd]; }
  __syncthreads();
  conv_chunk(s_r, &wbuf[o*97], cq*8, 32, acc);
  #pragma unroll
  for (int t=0;t<12;++t) atomicAdd(&s_b[t][o], acc[t]);
  __syncthreads();

  // write backcast + stage fc chunk0 + init fc accumulator (reuse s_qkv[0..768))
  for (int i=tid;i<768;i+=256){ int oo=i/12, t=i-oo*12; out[(size_t)nd*768 + i] = s_b[t][oo]; }
  for (int i=tid;i<6144;i+=256){ int oo=i/96, cd=i%96; wbuf[oo*97+cd] = fc_w[oo*192+cd]; }
  for (int i=tid;i<768;i+=256) s_qkv[i] = fc_b[i&63];
  __syncthreads();

  // forecast conv
  #pragma unroll
  for (int t=0;t<12;++t) acc[t]=0.f;
  conv_chunk(s_r, &wbuf[o*97], cq*8, 0, acc);
  __syncthreads();
  for (int i=tid;i<6144;i+=256){ int oo=i/96, cd=i%96; wbuf[oo*97+cd] = fc_w[oo*192+96+cd]; }
  __syncthreads();
  conv_chunk(s_r, &wbuf[o*97], cq*8, 32, acc);
  #pragma unroll
  for (int t=0;t<12;++t) atomicAdd(&s_qkv[t*64+o], acc[t]);
  __syncthreads();
  for (int i=tid;i<768;i+=256){ int oo=i/12, t=i-oo*12; out[30720000 + (size_t)nd*768 + i] = s_qkv[t*64+oo]; }
}

// ---------------- host ----------------
extern "C" void kernel_launch(void* const* d_in, const int* in_sizes, int n_in,
                              void* d_out, int out_size, void* d_ws, size_t ws_size,
                              hipStream_t stream){
  const float* x      = (const float*)d_in[0];
  const int*   ei     = (const int*)d_in[1];
  const float* cheb_w = (const float*)d_in[2];
  const float* cheb_b = (const float*)d_in[3];
  const float* gat_w  = (const float*)d_in[4];
  const float* att_src= (const float*)d_in[5];
  const float* att_dst= (const float*)d_in[6];
  const float* gat_b  = (const float*)d_in[7];
  const float* tc_w   = (const float*)d_in[8];
  const float* tc_b   = (const float*)d_in[9];
  const float* in_w   = (const float*)d_in[10];
  const float* in_b   = (const float*)d_in[11];
  const float* out_w  = (const float*)d_in[12];
  const float* out_b  = (const float*)d_in[13];
  const float* res_w  = (const float*)d_in[14];
  const float* res_b  = (const float*)d_in[15];
  const float* ln_g   = (const float*)d_in[16];
  const float* ln_b   = (const float*)d_in[17];
  const float* bc_w   = (const float*)d_in[18];
  const float* bc_b   = (const float*)d_in[19];
  const float* fc_w   = (const float*)d_in[20];
  const float* fc_b   = (const float*)d_in[21];
  float* out = (float*)d_out;

  char* w = (char*)d_ws;
  size_t off = 0;
  auto alloc = [&](size_t bytes)->void*{ void* p = w + off; off += (bytes + 255) & ~(size_t)255; return p; };
  int*   degcnt = (int*)alloc((size_t)BN*4);
  int*   cnt    = (int*)alloc((size_t)BN*4);
  int*   rowptr = (int*)alloc((size_t)(BN+1)*4);
  int*   cursor = (int*)alloc((size_t)BN*4);
  int*   esrc   = (int*)alloc((size_t)EE*4);
  float* ew     = (float*)alloc((size_t)EE*4);
  float* tx1    = (float*)alloc((size_t)BN*TT*4);
  float* tx2    = (float*)alloc((size_t)BN*TT*4);
  float* gwb    = (float*)alloc(1024*4);
  float* dis    = (float*)alloc((size_t)BN*4);
  float* sp     = (float*)alloc((size_t)BN*TT*64*4);
  if (off > ws_size){
    // fallback: stash sp in the backcast half of d_out; k_temporal reads each node's
    // sp window before overwriting it with that node's backcast (disjoint per block).
    sp = out;
  }

  hipMemsetAsync(degcnt, 0, (size_t)BN*4, stream);
  hipMemsetAsync(cnt,    0, (size_t)BN*4, stream);
  k_hist   <<<(EE+255)/256, 256, 0, stream>>>(ei, degcnt, cnt);
  k_dis    <<<(BN+255)/256, 256, 0, stream>>>(degcnt, dis);
  k_scan   <<<1, 1024, 0, stream>>>(cnt, rowptr, cursor);
  k_scatter<<<(EE+255)/256, 256, 0, stream>>>(ei, dis, cursor, esrc, ew);
  k_prop1  <<<(BN*TT+255)/256, 256, 0, stream>>>(x, rowptr, esrc, ew, tx1);
  k_prop2  <<<(BN*TT+255)/256, 256, 0, stream>>>(x, tx1, rowptr, esrc, ew, tx2);
  k_precomp<<<1, 128, 0, stream>>>(cheb_w, cheb_b, gat_w, att_src, att_dst, gwb);
  k_gat    <<<BN*TT/4, 256, 0, stream>>>(x, tx1, tx2, rowptr, esrc, gwb, gat_b, sp);
  k_temporal<<<BN, 256, 0, stream>>>(sp, x, tc_w, tc_b, in_w, in_b, out_w, out_b,
                                     res_w, res_b, ln_g, ln_b, bc_w, bc_b, fc_w, fc_b, out);
}

// Round 3
// 766.311 us; speedup vs baseline: 4.9952x; 4.9952x over previous
//
#include <hip/hip_runtime.h>

#define BN 40000
#define TT 12
#define EE 160000

typedef __attribute__((ext_vector_type(4))) float f32x4;
typedef __attribute__((ext_vector_type(4))) short s16x4;
typedef __attribute__((ext_vector_type(8))) short s16x8;

__device__ __forceinline__ float lrelu(float v){ return v > 0.f ? v : 0.2f*v; }

__device__ __forceinline__ short bf(float f){
  union { float f; unsigned u; } x; x.f = f;
  unsigned r = x.u + 0x7fffu + ((x.u >> 16) & 1u);
  return (short)(r >> 16);
}

// ---------------- graph preprocessing ----------------
__global__ void k_hist(const int* __restrict__ ei, int* __restrict__ degcnt, int* __restrict__ cnt){
  int e = blockIdx.x*256 + threadIdx.x;
  if (e < EE){
    atomicAdd(&degcnt[ei[e]], 1);      // src out-degree (ChebConv norm)
    atomicAdd(&cnt[ei[EE + e]], 1);    // dst in-degree (CSR)
  }
}

__global__ void k_dis(const int* __restrict__ degcnt, float* __restrict__ dis){
  int i = blockIdx.x*256 + threadIdx.x;
  if (i < BN){ int d = degcnt[i]; dis[i] = d > 0 ? rsqrtf((float)d) : 0.f; }
}

__global__ void k_scan(const int* __restrict__ cnt, int* __restrict__ rowptr, int* __restrict__ cursor){
  __shared__ int part[1024];
  int tid = threadIdx.x;
  const int CH = 40;
  int base = tid*CH;
  int s = 0;
  for (int j=0;j<CH;++j){ int idx=base+j; if (idx<BN) s += cnt[idx]; }
  part[tid] = s; __syncthreads();
  for (int off=1; off<1024; off<<=1){
    int v = (tid>=off)? part[tid-off] : 0;
    __syncthreads();
    part[tid] += v;
    __syncthreads();
  }
  int run = part[tid] - s;
  for (int j=0;j<CH;++j){ int idx=base+j; if (idx<BN){ rowptr[idx]=run; cursor[idx]=run; run += cnt[idx]; } }
  if (tid==1023) rowptr[BN] = part[1023];
}

__global__ void k_scatter(const int* __restrict__ ei, const float* __restrict__ dis,
                          int* __restrict__ cursor, int* __restrict__ esrc, float* __restrict__ ew){
  int e = blockIdx.x*256 + threadIdx.x;
  if (e < EE){
    int s = ei[e], d = ei[EE+e];
    int p = atomicAdd(&cursor[d], 1);
    esrc[p] = s;
    ew[p] = -dis[s]*dis[d];
  }
}

// ---------------- Cheb propagation (FIN=1 scalars) ----------------
__global__ void k_prop1(const float* __restrict__ x, const int* __restrict__ rowptr,
                        const int* __restrict__ esrc, const float* __restrict__ ew,
                        float* __restrict__ tx1){
  int i = blockIdx.x*256 + threadIdx.x;
  if (i >= BN*TT) return;
  int d = i/TT, t = i - d*TT;
  int r0 = rowptr[d], r1 = rowptr[d+1];
  float a = 0.f;
  for (int p=r0;p<r1;++p) a += ew[p]*x[esrc[p]*TT + t];
  tx1[i] = a;
}

__global__ void k_prop2(const float* __restrict__ x, const float* __restrict__ tx1,
                        const int* __restrict__ rowptr, const int* __restrict__ esrc,
                        const float* __restrict__ ew, float* __restrict__ tx2){
  int i = blockIdx.x*256 + threadIdx.x;
  if (i >= BN*TT) return;
  int d = i/TT, t = i - d*TT;
  int r0 = rowptr[d], r1 = rowptr[d+1];
  float a = 0.f;
  for (int p=r0;p<r1;++p) a += ew[p]*tx1[esrc[p]*TT + t];
  tx2[i] = 2.f*a - x[i];
}

// ---------------- fold cheb_w/cheb_b through gat_w / att vectors ----------------
__global__ void k_precomp(const float* __restrict__ cheb_w, const float* __restrict__ cheb_b,
                          const float* __restrict__ gat_w, const float* __restrict__ att_src,
                          const float* __restrict__ att_dst, float* __restrict__ gwbuf){
  __shared__ float sgw[384]; __shared__ float sgc[128];
  int hc = threadIdx.x; // 128 threads
  for (int k=0;k<3;++k){
    float a=0; for (int c=0;c<64;++c) a += cheb_w[k*64+c]*gat_w[hc*64+c];
    sgw[k*128+hc]=a; gwbuf[k*128+hc]=a;
  }
  { float g=0; for (int c=0;c<64;++c) g += cheb_b[c]*gat_w[hc*64+c]; sgc[hc]=g; gwbuf[384+hc]=g; }
  __syncthreads();
  if (hc<6){ int k=hc>>1, h=hc&1; float a=0,d=0;
    for (int c=0;c<64;++c){ float g=sgw[k*128+h*64+c]; a+=g*att_src[h*64+c]; d+=g*att_dst[h*64+c]; }
    gwbuf[512+hc]=a; gwbuf[518+hc]=d; }
  if (hc<2){ float a=0,d=0;
    for (int c=0;c<64;++c){ float g=sgc[hc*64+c]; a+=g*att_src[hc*64+c]; d+=g*att_dst[hc*64+c]; }
    gwbuf[524+hc]=a; gwbuf[526+hc]=d; }
}

// ---------------- GAT: one wave per (node,t), lane = feature ----------------
__global__ __launch_bounds__(256) void k_gat(const float* __restrict__ x, const float* __restrict__ tx1,
     const float* __restrict__ tx2, const int* __restrict__ rowptr, const int* __restrict__ esrc,
     const float* __restrict__ gwbuf, const float* __restrict__ gat_b, float* __restrict__ sp){
  int wave = (blockIdx.x<<2) + (threadIdx.x>>6);
  int lane = threadIdx.x & 63;
  int d = wave/TT, t = wave - d*TT;

  float ga0 = gwbuf[lane],      ga1 = gwbuf[128+lane], ga2 = gwbuf[256+lane], gac = gwbuf[384+lane];
  float gb0 = gwbuf[64+lane],   gb1 = gwbuf[192+lane], gb2 = gwbuf[320+lane], gbc = gwbuf[448+lane];
  float as00=gwbuf[512], as01=gwbuf[513], as10=gwbuf[514], as11=gwbuf[515], as20=gwbuf[516], as21=gwbuf[517];
  float ad00=gwbuf[518], ad01=gwbuf[519], ad10=gwbuf[520], ad11=gwbuf[521], ad20=gwbuf[522], ad21=gwbuf[523];
  float asc0=gwbuf[524], asc1=gwbuf[525], adc0=gwbuf[526], adc1=gwbuf[527];

  int r0 = rowptr[d], r1 = rowptr[d+1];
  float td0 = x[d*TT+t], td1 = tx1[d*TT+t], td2 = tx2[d*TT+t];
  float adh0 = td0*ad00 + td1*ad10 + td2*ad20 + adc0;
  float adh1 = td0*ad01 + td1*ad11 + td2*ad21 + adc1;
  float es0 = lrelu(td0*as00 + td1*as10 + td2*as20 + asc0 + adh0);
  float es1 = lrelu(td0*as01 + td1*as11 + td2*as21 + asc1 + adh1);
  float m0 = es0, m1 = es1;
  for (int p=r0;p<r1;++p){
    int s = esrc[p];
    float s0 = x[s*TT+t], s1 = tx1[s*TT+t], s2 = tx2[s*TT+t];
    m0 = fmaxf(m0, lrelu(s0*as00 + s1*as10 + s2*as20 + asc0 + adh0));
    m1 = fmaxf(m1, lrelu(s0*as01 + s1*as11 + s2*as21 + asc1 + adh1));
  }
  float z0, z1, acc0, acc1;
  { float p0 = __expf(es0 - m0), p1 = __expf(es1 - m1);
    z0 = p0; z1 = p1;
    acc0 = p0*(td0*ga0 + td1*ga1 + td2*ga2 + gac);
    acc1 = p1*(td0*gb0 + td1*gb1 + td2*gb2 + gbc); }
  for (int p=r0;p<r1;++p){
    int s = esrc[p];
    float s0 = x[s*TT+t], s1 = tx1[s*TT+t], s2 = tx2[s*TT+t];
    float e0 = lrelu(s0*as00 + s1*as10 + s2*as20 + asc0 + adh0);
    float e1 = lrelu(s0*as01 + s1*as11 + s2*as21 + asc1 + adh1);
    float p0 = __expf(e0 - m0), p1 = __expf(e1 - m1);
    z0 += p0; z1 += p1;
    acc0 += p0*(s0*ga0 + s1*ga1 + s2*ga2 + gac);
    acc1 += p1*(s0*gb0 + s1*gb1 + s2*gb2 + gbc);
  }
  sp[wave*64 + lane] = 0.5f*(acc0/z0 + acc1/z1) + gat_b[lane];
}

// ---------------- bf16 weight pre-pack (B-fragment layouts, 72-col padded) ----------------
// layout in wpack (shorts):
//   [0,13824)      wtc : [dt][o][c72]  = tc_w[o*192 + c*3 + dt]
//   [13824,27648)  wqkv: [j][k72]      = in_w[j*64 + k]
//   [27648,32256)  wout: [o][c72]      = out_w[o*64 + c]
//   [32256,46080)  wbc : [dt][o][c72]
//   [46080,59904)  wfc : [dt][o][c72]
__global__ void k_prepw(const float* __restrict__ tc_w, const float* __restrict__ in_w,
                        const float* __restrict__ out_w, const float* __restrict__ bc_w,
                        const float* __restrict__ fc_w, short* __restrict__ wp){
  int i = blockIdx.x*256 + threadIdx.x;
  if (i >= 59904) return;
  float v;
  if (i < 13824){ int dt=i/4608, r=i%4608, o=r/72, c=r%72; v = (c<64)? tc_w[o*192+c*3+dt] : 0.f; }
  else if (i < 27648){ int d=i-13824; int j=d/72, k=d%72; v = (k<64)? in_w[j*64+k] : 0.f; }
  else if (i < 32256){ int d=i-27648; int o=d/72, c=d%72; v = (c<64)? out_w[o*64+c] : 0.f; }
  else if (i < 46080){ int d=i-32256; int dt=d/4608, r=d%4608, o=r/72, c=r%72; v = (c<64)? bc_w[o*192+c*3+dt] : 0.f; }
  else               { int d=i-46080; int dt=d/4608, r=d%4608, o=r/72, c=r%72; v = (c<64)? fc_w[o*192+c*3+dt] : 0.f; }
  wp[i] = bf(v);
}

// ---------------- MFMA temporal pipeline ----------------
__device__ __forceinline__ void stage16(short* dst, const short* src, int n16, int tid){
  for (int i=tid; i<n16; i+=256) ((float4*)dst)[i] = ((const float4*)src)[i];
}

// conv as 3 row-shifted GEMMs: acc[nt] over 4 n-tiles (64 outputs), K=64 per tap.
__device__ __forceinline__ void conv_gemm(const short* __restrict__ abuf, const short* __restrict__ wv,
                                          int arow0, int l15, int l4, f32x4 acc[4]){
  #pragma unroll
  for (int dt=0; dt<3; ++dt){
    #pragma unroll
    for (int kc=0; kc<2; ++kc){
      s16x8 a = *(const s16x8*)&abuf[(arow0 + l15 + dt)*72 + kc*32 + l4*8];
      #pragma unroll
      for (int nt=0; nt<4; ++nt){
        s16x8 b = *(const s16x8*)&wv[(dt*64 + nt*16 + l15)*72 + kc*32 + l4*8];
        acc[nt] = __builtin_amdgcn_mfma_f32_16x16x32_bf16(a, b, acc[nt], 0, 0, 0);
      }
    }
  }
}

__global__ __launch_bounds__(256) void k_temporal2(
  const float* __restrict__ sp, const float* __restrict__ x, const short* __restrict__ wpack,
  const float* __restrict__ tc_b, const float* __restrict__ in_b,
  const float* __restrict__ out_b, const float* __restrict__ res_w, const float* __restrict__ res_b,
  const float* __restrict__ ln_g, const float* __restrict__ ln_b,
  const float* __restrict__ bc_b, const float* __restrict__ fc_b,
  float* __restrict__ out)
{
  // pools (aliased across phases). rows are 72 bf16 (144B) -> 2-way-bank-conflict b128 reads.
  __shared__ __align__(16) short poolA[66*72];   // spbuf (u=t+1, +2 guard rows) -> Qbuf
  __shared__ __align__(16) short poolB[64*72];   // tcbuf -> obuf
  __shared__ __align__(16) short poolC[66*72];   // Kbuf  -> Rbuf (LN result, u=t+1, +2 guard)
  __shared__ __align__(16) short vtbuf[256*24];  // V^T: [(node*4+h)*16+dh][t(24pad)]
  __shared__ __align__(16) short pbuf[64*24];    // P scratch: [(node)*16+q][kt(24pad)]
  __shared__ __align__(16) short wbuf[13824];    // staged weights (reused per phase)

  const int tid = threadIdx.x;
  const int w   = tid >> 6;       // wave == node (0..3)
  const int lane = tid & 63;
  const int l15 = lane & 15, l4 = lane >> 4;
  const int ndb = blockIdx.x * 4;

  const f32x4 z4 = {0.f,0.f,0.f,0.f};
  s16x8 zf; 
  #pragma unroll
  for (int j=0;j<8;++j) zf[j]=0;

  // ---- phase 0: stage sp (fp32->bf16, shifted rows) + zero pad rows + stage tc weights
  for (int i=tid; i<648; i+=256){           // 18 zero rows x 36 ints
    int rr=i/36, cc=i%36;
    int row = (rr<16) ? ((rr>>2)*16 + (((rr&3)==0)?0:(12+(rr&3)))) : (64 + rr - 16);
    ((int*)poolA)[row*36 + cc] = 0;
  }
  for (int i=tid; i<768; i+=256){           // 4 nodes x 192 float4 chunks
    int node=i/192, rem=i%192, t=rem/16, c4=(rem&15)*4;
    float4 v = *(const float4*)&sp[(size_t)(ndb+node)*768 + t*64 + c4];
    s16x4 p; p.x=bf(v.x); p.y=bf(v.y); p.z=bf(v.z); p.w=bf(v.w);
    *(s16x4*)&poolA[(node*16 + t + 1)*72 + c4] = p;
  }
  stage16(wbuf, wpack + 0, 1728, tid);
  __syncthreads();

  // ---- phase 1: tc conv GEMM -> tcbuf (bf16, +bias)
  {
    f32x4 acc[4] = {z4,z4,z4,z4};
    conv_gemm(poolA, wbuf, w*16, l15, l4, acc);
    #pragma unroll
    for (int nt=0; nt<4; ++nt){
      float bb = tc_b[nt*16 + l15];
      #pragma unroll
      for (int r=0; r<4; ++r)
        poolB[(w*16 + l4*4 + r)*72 + nt*16 + l15] = bf(acc[nt][r] + bb);
    }
  }
  __syncthreads();
  stage16(wbuf, wpack + 13824, 1728, tid);
  __syncthreads();

  // ---- phase 2: QKV GEMM (A = own tcbuf rows) -> Qbuf(poolA), Kbuf(poolC), V^T(vtbuf)
  {
    s16x8 a0 = *(const s16x8*)&poolB[(w*16+l15)*72 +  0 + l4*8];
    s16x8 a1 = *(const s16x8*)&poolB[(w*16+l15)*72 + 32 + l4*8];
    #pragma unroll
    for (int grp=0; grp<3; ++grp){
      f32x4 acc[4] = {z4,z4,z4,z4};
      #pragma unroll
      for (int nt=0; nt<4; ++nt){
        s16x8 b0 = *(const s16x8*)&wbuf[((grp*4+nt)*16 + l15)*72 +  0 + l4*8];
        acc[nt] = __builtin_amdgcn_mfma_f32_16x16x32_bf16(a0, b0, acc[nt], 0,0,0);
        s16x8 b1 = *(const s16x8*)&wbuf[((grp*4+nt)*16 + l15)*72 + 32 + l4*8];
        acc[nt] = __builtin_amdgcn_mfma_f32_16x16x32_bf16(a1, b1, acc[nt], 0,0,0);
      }
      #pragma unroll
      for (int nt=0; nt<4; ++nt){
        float bb = in_b[(grp*4+nt)*16 + l15];
        if (grp==0){
          #pragma unroll
          for (int r=0;r<4;++r) poolA[(w*16 + l4*4 + r)*72 + nt*16 + l15] = bf(acc[nt][r] + bb);
        } else if (grp==1){
          #pragma unroll
          for (int r=0;r<4;++r) poolC[(w*16 + l4*4 + r)*72 + nt*16 + l15] = bf(acc[nt][r] + bb);
        } else {  // V: h == nt, dh == l15; write transposed, 4 consecutive t -> b64
          s16x4 pk;
          pk.x=bf(acc[nt][0]+bb); pk.y=bf(acc[nt][1]+bb); pk.z=bf(acc[nt][2]+bb); pk.w=bf(acc[nt][3]+bb);
          *(s16x4*)&vtbuf[((w*4 + nt)*16 + l15)*24 + l4*4] = pk;
        }
      }
    }
  }
  __syncthreads();

  // ---- phase 3: stage out_w + attention (per wave: own node, 4 heads; MFMA with K zero-padded)
  stage16(wbuf, wpack + 27648, 576, tid);
  {
    #pragma unroll 1
    for (int h=0; h<4; ++h){
      s16x8 qa = zf, kb = zf;
      if (l4 < 2){
        qa = *(const s16x8*)&poolA[(w*16 + l15)*72 + h*16 + l4*8];   // Q[q][dh]
        kb = *(const s16x8*)&poolC[(w*16 + l15)*72 + h*16 + l4*8];   // K[kt][dh] (B^T form)
      }
      f32x4 sc = __builtin_amdgcn_mfma_f32_16x16x32_bf16(qa, kb, z4, 0,0,0);  // col=kt,row=q
      float invz[4];
      #pragma unroll
      for (int r=0; r<4; ++r){
        float s = (l15 < 12) ? sc[r]*0.25f : -3.0e38f;
        float m = s;
        #pragma unroll
        for (int dd=1; dd<16; dd<<=1) m = fmaxf(m, __shfl_xor(m, dd));
        float e = __expf(s - m);
        float z = e;
        #pragma unroll
        for (int dd=1; dd<16; dd<<=1) z += __shfl_xor(z, dd);
        invz[r] = 1.f/z;
        pbuf[(w*16 + l4*4 + r)*24 + l15] = bf(e);
      }
      s16x8 pa = zf, vb = zf;
      if (l4 < 2){
        pa = *(const s16x8*)&pbuf[(w*16 + l15)*24 + l4*8];                   // P[q][kt]
        vb = *(const s16x8*)&vtbuf[((w*4 + h)*16 + l15)*24 + l4*8];          // V^T[dh][kt]
      }
      f32x4 ov = __builtin_amdgcn_mfma_f32_16x16x32_bf16(pa, vb, z4, 0,0,0); // col=dh,row=q
      #pragma unroll
      for (int r=0; r<4; ++r)
        poolB[(w*16 + l4*4 + r)*72 + h*16 + l15] = bf(ov[r]*invz[r]);        // obuf
    }
  }
  __syncthreads();

  // ---- phase 4: out-proj GEMM + residual + relu + LayerNorm -> Rbuf(poolC, u=t+1)
  // zero Rbuf pad rows (own node) + guard rows
  for (int i=lane; i<144; i+=64){
    int sel=i/36, cc=i%36;
    int u = (sel==0)?0:(12+sel);
    ((int*)poolC)[(w*16+u)*36 + cc] = 0;
  }
  if (w==3) for (int i=lane; i<72; i+=64) ((int*)poolC)[64*36 + i] = 0;
  {
    s16x8 a0 = *(const s16x8*)&poolB[(w*16+l15)*72 +  0 + l4*8];
    s16x8 a1 = *(const s16x8*)&poolB[(w*16+l15)*72 + 32 + l4*8];
    f32x4 acc[4] = {z4,z4,z4,z4};
    #pragma unroll
    for (int nt=0; nt<4; ++nt){
      s16x8 b0 = *(const s16x8*)&wbuf[(nt*16 + l15)*72 +  0 + l4*8];
      acc[nt] = __builtin_amdgcn_mfma_f32_16x16x32_bf16(a0, b0, acc[nt], 0,0,0);
      s16x8 b1 = *(const s16x8*)&wbuf[(nt*16 + l15)*72 + 32 + l4*8];
      acc[nt] = __builtin_amdgcn_mfma_f32_16x16x32_bf16(a1, b1, acc[nt], 0,0,0);
    }
    float xr[4];
    #pragma unroll
    for (int r=0; r<4; ++r){ int t=l4*4+r; xr[r] = (t<12) ? x[(size_t)(ndb+w)*12 + t] : 0.f; }
    float zr[4][4], sum[4]={0,0,0,0}, sq[4]={0,0,0,0};
    #pragma unroll
    for (int nt=0; nt<4; ++nt){
      int o = nt*16 + l15;
      float ob=out_b[o], rw=res_w[o], rb=res_b[o];
      #pragma unroll
      for (int r=0; r<4; ++r){
        float v = acc[nt][r] + ob + xr[r]*rw + rb;
        v = v>0.f ? v : 0.f;
        zr[nt][r]=v; sum[r]+=v; sq[r]+=v*v;
      }
    }
    #pragma unroll
    for (int r=0; r<4; ++r){
      #pragma unroll
      for (int dd=1; dd<16; dd<<=1){ sum[r]+=__shfl_xor(sum[r],dd); sq[r]+=__shfl_xor(sq[r],dd); }
    }
    if (l4 < 3){
      #pragma unroll
      for (int r=0; r<4; ++r){
        float mu = sum[r]*(1.f/64.f);
        float va = sq[r]*(1.f/64.f) - mu*mu;
        float iv = rsqrtf(fmaxf(va,0.f) + 1e-5f);
        #pragma unroll
        for (int nt=0; nt<4; ++nt){
          int o = nt*16 + l15;
          int t = l4*4 + r;
          poolC[(w*16 + t + 1)*72 + o] = bf((zr[nt][r]-mu)*iv*ln_g[o] + ln_b[o]);
        }
      }
    }
  }
  __syncthreads();
  stage16(wbuf, wpack + 32256, 1728, tid);
  __syncthreads();

  // ---- phase 5: backcast conv GEMM -> out
  {
    f32x4 acc[4] = {z4,z4,z4,z4};
    conv_gemm(poolC, wbuf, w*16, l15, l4, acc);
    if (l4 < 3){
      #pragma unroll
      for (int nt=0; nt<4; ++nt){
        int o = nt*16 + l15; float bb = bc_b[o];
        float4 v; v.x=acc[nt][0]+bb; v.y=acc[nt][1]+bb; v.z=acc[nt][2]+bb; v.w=acc[nt][3]+bb;
        *(float4*)&out[(size_t)(ndb+w)*768 + o*12 + l4*4] = v;
      }
    }
  }
  __syncthreads();
  stage16(wbuf, wpack + 46080, 1728, tid);
  __syncthreads();

  // ---- phase 6: forecast conv GEMM -> out
  {
    f32x4 acc[4] = {z4,z4,z4,z4};
    conv_gemm(poolC, wbuf, w*16, l15, l4, acc);
    if (l4 < 3){
      #pragma unroll
      for (int nt=0; nt<4; ++nt){
        int o = nt*16 + l15; float bb = fc_b[o];
        float4 v; v.x=acc[nt][0]+bb; v.y=acc[nt][1]+bb; v.z=acc[nt][2]+bb; v.w=acc[nt][3]+bb;
        *(float4*)&out[30720000 + (size_t)(ndb+w)*768 + o*12 + l4*4] = v;
      }
    }
  }
}

// ---------------- host ----------------
extern "C" void kernel_launch(void* const* d_in, const int* in_sizes, int n_in,
                              void* d_out, int out_size, void* d_ws, size_t ws_size,
                              hipStream_t stream){
  const float* x      = (const float*)d_in[0];
  const int*   ei     = (const int*)d_in[1];
  const float* cheb_w = (const float*)d_in[2];
  const float* cheb_b = (const float*)d_in[3];
  const float* gat_w  = (const float*)d_in[4];
  const float* att_src= (const float*)d_in[5];
  const float* att_dst= (const float*)d_in[6];
  const float* gat_b  = (const float*)d_in[7];
  const float* tc_w   = (const float*)d_in[8];
  const float* tc_b   = (const float*)d_in[9];
  const float* in_w   = (const float*)d_in[10];
  const float* in_b   = (const float*)d_in[11];
  const float* out_w  = (const float*)d_in[12];
  const float* out_b  = (const float*)d_in[13];
  const float* res_w  = (const float*)d_in[14];
  const float* res_b  = (const float*)d_in[15];
  const float* ln_g   = (const float*)d_in[16];
  const float* ln_b   = (const float*)d_in[17];
  const float* bc_w   = (const float*)d_in[18];
  const float* bc_b   = (const float*)d_in[19];
  const float* fc_w   = (const float*)d_in[20];
  const float* fc_b   = (const float*)d_in[21];
  float* out = (float*)d_out;

  char* w = (char*)d_ws;
  size_t off = 0;
  auto alloc = [&](size_t bytes)->void*{ void* p = w + off; off += (bytes + 255) & ~(size_t)255; return p; };
  int*   degcnt = (int*)alloc((size_t)BN*4);
  int*   cnt    = (int*)alloc((size_t)BN*4);
  int*   rowptr = (int*)alloc((size_t)(BN+1)*4);
  int*   cursor = (int*)alloc((size_t)BN*4);
  int*   esrc   = (int*)alloc((size_t)EE*4);
  float* ew     = (float*)alloc((size_t)EE*4);
  float* tx1    = (float*)alloc((size_t)BN*TT*4);
  float* tx2    = (float*)alloc((size_t)BN*TT*4);
  float* gwb    = (float*)alloc(1024*4);
  float* dis    = (float*)alloc((size_t)BN*4);
  short* wpack  = (short*)alloc((size_t)59904*2);
  float* sp     = (float*)alloc((size_t)BN*TT*64*4);
  if (off > ws_size){
    // fallback: stash sp in the backcast half of d_out; k_temporal2 reads each node's
    // sp window before overwriting it with that node's backcast (disjoint per block).
    sp = out;
  }

  hipMemsetAsync(degcnt, 0, (size_t)BN*4, stream);
  hipMemsetAsync(cnt,    0, (size_t)BN*4, stream);
  k_hist   <<<(EE+255)/256, 256, 0, stream>>>(ei, degcnt, cnt);
  k_dis    <<<(BN+255)/256, 256, 0, stream>>>(degcnt, dis);
  k_scan   <<<1, 1024, 0, stream>>>(cnt, rowptr, cursor);
  k_scatter<<<(EE+255)/256, 256, 0, stream>>>(ei, dis, cursor, esrc, ew);
  k_prop1  <<<(BN*TT+255)/256, 256, 0, stream>>>(x, rowptr, esrc, ew, tx1);
  k_prop2  <<<(BN*TT+255)/256, 256, 0, stream>>>(x, tx1, rowptr, esrc, ew, tx2);
  k_precomp<<<1, 128, 0, stream>>>(cheb_w, cheb_b, gat_w, att_src, att_dst, gwb);
  k_prepw  <<<(59904+255)/256, 256, 0, stream>>>(tc_w, in_w, out_w, bc_w, fc_w, wpack);
  k_gat    <<<BN*TT/4, 256, 0, stream>>>(x, tx1, tx2, rowptr, esrc, gwb, gat_b, sp);
  k_temporal2<<<BN/4, 256, 0, stream>>>(sp, x, wpack, tc_b, in_b, out_b, res_w, res_b,
                                        ln_g, ln_b, bc_b, fc_b, out);
}

// Round 4
// 445.567 us; speedup vs baseline: 8.5911x; 1.7199x over previous
//
#include <hip/hip_runtime.h>

#define BN 40000
#define TT 12
#define EE 160000

typedef __attribute__((ext_vector_type(4))) float f32x4;
typedef __attribute__((ext_vector_type(4))) short s16x4;
typedef __attribute__((ext_vector_type(8))) short s16x8;

__device__ __forceinline__ float lrelu(float v){ return v > 0.f ? v : 0.2f*v; }

__device__ __forceinline__ short bf(float f){
  union { float f; unsigned u; } x; x.f = f;
  unsigned r = x.u + 0x7fffu + ((x.u >> 16) & 1u);
  return (short)(r >> 16);
}

#define GLOAD_LDS16(g, l) __builtin_amdgcn_global_load_lds( \
    (const __attribute__((address_space(1))) void*)(g), \
    (__attribute__((address_space(3))) void*)(l), 16, 0, 0)

// ---------------- graph preprocessing ----------------
__global__ void k_hist(const int* __restrict__ ei, int* __restrict__ degcnt, int* __restrict__ cnt){
  int e = blockIdx.x*256 + threadIdx.x;
  if (e < EE){
    atomicAdd(&degcnt[ei[e]], 1);      // src out-degree (ChebConv norm)
    atomicAdd(&cnt[ei[EE + e]], 1);    // dst in-degree (CSR)
  }
}

__global__ void k_dis(const int* __restrict__ degcnt, float* __restrict__ dis){
  int i = blockIdx.x*256 + threadIdx.x;
  if (i < BN){ int d = degcnt[i]; dis[i] = d > 0 ? rsqrtf((float)d) : 0.f; }
}

__global__ void k_scan(const int* __restrict__ cnt, int* __restrict__ rowptr, int* __restrict__ cursor){
  __shared__ int part[1024];
  int tid = threadIdx.x;
  const int CH = 40;
  int base = tid*CH;
  int s = 0;
  for (int j=0;j<CH;++j){ int idx=base+j; if (idx<BN) s += cnt[idx]; }
  part[tid] = s; __syncthreads();
  for (int off=1; off<1024; off<<=1){
    int v = (tid>=off)? part[tid-off] : 0;
    __syncthreads();
    part[tid] += v;
    __syncthreads();
  }
  int run = part[tid] - s;
  for (int j=0;j<CH;++j){ int idx=base+j; if (idx<BN){ rowptr[idx]=run; cursor[idx]=run; run += cnt[idx]; } }
  if (tid==1023) rowptr[BN] = part[1023];
}

__global__ void k_scatter(const int* __restrict__ ei, const float* __restrict__ dis,
                          int* __restrict__ cursor, int* __restrict__ esrc, float* __restrict__ ew){
  int e = blockIdx.x*256 + threadIdx.x;
  if (e < EE){
    int s = ei[e], d = ei[EE+e];
    int p = atomicAdd(&cursor[d], 1);
    esrc[p] = s;
    ew[p] = -dis[s]*dis[d];
  }
}

// ---------------- Cheb propagation, vectorized: thread = (node, t-quarter) ----------------
__global__ void k_prop1v(const float* __restrict__ x, const int* __restrict__ rowptr,
                         const int* __restrict__ esrc, const float* __restrict__ ew,
                         float* __restrict__ tx1){
  int i = blockIdx.x*256 + threadIdx.x;
  if (i >= BN*3) return;
  int d = i/3, q = i - d*3;
  int r0 = rowptr[d], r1 = rowptr[d+1];
  float4 a = {0.f,0.f,0.f,0.f};
  for (int p=r0;p<r1;++p){
    float wv = ew[p];
    float4 v = ((const float4*)x)[esrc[p]*3 + q];
    a.x += wv*v.x; a.y += wv*v.y; a.z += wv*v.z; a.w += wv*v.w;
  }
  ((float4*)tx1)[i] = a;
}

__global__ void k_prop2v(const float* __restrict__ x, const float* __restrict__ tx1,
                         const int* __restrict__ rowptr, const int* __restrict__ esrc,
                         const float* __restrict__ ew, float* __restrict__ tx2){
  int i = blockIdx.x*256 + threadIdx.x;
  if (i >= BN*3) return;
  int d = i/3, q = i - d*3;
  int r0 = rowptr[d], r1 = rowptr[d+1];
  float4 a = {0.f,0.f,0.f,0.f};
  for (int p=r0;p<r1;++p){
    float wv = ew[p];
    float4 v = ((const float4*)tx1)[esrc[p]*3 + q];
    a.x += wv*v.x; a.y += wv*v.y; a.z += wv*v.z; a.w += wv*v.w;
  }
  float4 xv = ((const float4*)x)[i];
  float4 o; o.x = 2.f*a.x - xv.x; o.y = 2.f*a.y - xv.y; o.z = 2.f*a.z - xv.z; o.w = 2.f*a.w - xv.w;
  ((float4*)tx2)[i] = o;
}

// ---------------- fold cheb_w/cheb_b through gat_w / att vectors ----------------
// gwbuf: [k*128+hc] k<3 (384) | gc 384..511 | ask 512+k*2+h | adk 518+k*2+h | asc 524+h | adc 526+h
__global__ void k_precomp(const float* __restrict__ cheb_w, const float* __restrict__ cheb_b,
                          const float* __restrict__ gat_w, const float* __restrict__ att_src,
                          const float* __restrict__ att_dst, float* __restrict__ gwbuf){
  __shared__ float sgw[384]; __shared__ float sgc[128];
  int hc = threadIdx.x; // 128 threads
  for (int k=0;k<3;++k){
    float a=0; for (int c=0;c<64;++c) a += cheb_w[k*64+c]*gat_w[hc*64+c];
    sgw[k*128+hc]=a; gwbuf[k*128+hc]=a;
  }
  { float g=0; for (int c=0;c<64;++c) g += cheb_b[c]*gat_w[hc*64+c]; sgc[hc]=g; gwbuf[384+hc]=g; }
  __syncthreads();
  if (hc<6){ int k=hc>>1, h=hc&1; float a=0,d=0;
    for (int c=0;c<64;++c){ float g=sgw[k*128+h*64+c]; a+=g*att_src[h*64+c]; d+=g*att_dst[h*64+c]; }
    gwbuf[512+hc]=a; gwbuf[518+hc]=d; }
  if (hc<2){ float a=0,d=0;
    for (int c=0;c<64;++c){ float g=sgc[hc*64+c]; a+=g*att_src[hc*64+c]; d+=g*att_dst[hc*64+c]; }
    gwbuf[524+hc]=a; gwbuf[526+hc]=d; }
}

// ---------------- fold G (ga/gb) + gbase through tc_w: gwtc [64][40] bf16, btc [16][64] f32 ----------------
__global__ void k_precomp2(const float* __restrict__ gwbuf, const float* __restrict__ tc_w,
                           const float* __restrict__ tc_b, const float* __restrict__ gat_b,
                           short* __restrict__ gwtc, float* __restrict__ btc){
  int o = threadIdx.x;  // 64 threads
  if (o >= 64) return;
  float sbias[3];
  for (int dt=0; dt<3; ++dt){
    float s[6] = {0,0,0,0,0,0};
    float sb = 0.f;
    for (int c=0;c<64;++c){
      float wv = tc_w[o*192 + c*3 + dt];
      for (int j=0;j<3;++j){
        s[j]   += wv * gwbuf[j*128 + c];
        s[3+j] += wv * gwbuf[j*128 + 64 + c];
      }
      sb += wv * (gat_b[c] + 0.5f*(gwbuf[384+c] + gwbuf[448+c]));
    }
    for (int j=0;j<6;++j) gwtc[o*40 + dt*6 + j] = bf(s[j]);
    sbias[dt] = sb;
  }
  for (int k=18;k<40;++k) gwtc[o*40+k] = 0;
  for (int t=0;t<16;++t){
    float b = tc_b[o];
    if (t < 12){
      if (t > 0)  b += sbias[0];
      b += sbias[1];
      if (t < 11) b += sbias[2];
    }
    btc[t*64+o] = b;
  }
}

// ---------------- GAT: thread = (node, t-quarter, head); single-pass softmax + linearity ----------------
__global__ __launch_bounds__(256) void k_gat3(const float* __restrict__ x, const float* __restrict__ tx1,
     const float* __restrict__ tx2, const int* __restrict__ rowptr, const int* __restrict__ esrc,
     const float* __restrict__ gwbuf, float* __restrict__ coef, int cst){
  int i = blockIdx.x*256 + threadIdx.x;
  if (i >= BN*6) return;
  int d = i/6, r = i - d*6;
  int q = r >> 1, h = r & 1;

  float as0 = gwbuf[512+0+h], as1 = gwbuf[512+2+h], as2 = gwbuf[512+4+h];
  float ad0 = gwbuf[518+0+h], ad1 = gwbuf[518+2+h], ad2 = gwbuf[518+4+h];
  float asc = gwbuf[524+h],   adc = gwbuf[526+h];

  float4 t0 = ((const float4*)x)[d*3+q];
  float4 t1 = ((const float4*)tx1)[d*3+q];
  float4 t2 = ((const float4*)tx2)[d*3+q];
  float td0[4] = {t0.x,t0.y,t0.z,t0.w};
  float td1[4] = {t1.x,t1.y,t1.z,t1.w};
  float td2[4] = {t2.x,t2.y,t2.z,t2.w};

  float adh[4], S0[4], S1[4], S2[4], Z[4];
  #pragma unroll
  for (int t=0;t<4;++t){
    adh[t] = td0[t]*ad0 + td1[t]*ad1 + td2[t]*ad2 + adc;
    float es = lrelu(td0[t]*as0 + td1[t]*as1 + td2[t]*as2 + asc + adh[t]);
    float p = __expf(es);
    S0[t] = p*td0[t]; S1[t] = p*td1[t]; S2[t] = p*td2[t]; Z[t] = p;
  }
  int r0 = rowptr[d], r1 = rowptr[d+1];
  for (int p=r0;p<r1;++p){
    int s = esrc[p];
    float4 v0 = ((const float4*)x)[s*3+q];
    float4 v1 = ((const float4*)tx1)[s*3+q];
    float4 v2 = ((const float4*)tx2)[s*3+q];
    float s0[4] = {v0.x,v0.y,v0.z,v0.w};
    float s1[4] = {v1.x,v1.y,v1.z,v1.w};
    float s2[4] = {v2.x,v2.y,v2.z,v2.w};
    #pragma unroll
    for (int t=0;t<4;++t){
      float e = lrelu(s0[t]*as0 + s1[t]*as1 + s2[t]*as2 + asc + adh[t]);
      float pp = __expf(e);
      S0[t] += pp*s0[t]; S1[t] += pp*s1[t]; S2[t] += pp*s2[t]; Z[t] += pp;
    }
  }
  float* cw = coef + (size_t)d*cst + q*32;   // 4 t's x 8
  #pragma unroll
  for (int t=0;t<4;++t){
    float inv = 0.5f/Z[t];
    cw[t*8 + h*3 + 0] = S0[t]*inv;
    cw[t*8 + h*3 + 1] = S1[t]*inv;
    cw[t*8 + h*3 + 2] = S2[t]*inv;
  }
}

// ---------------- bf16 weight pre-pack (B-fragment layouts, 72-col padded) ----------------
// wpack layout (shorts): qkv [0,13824) | out [13824,18432) | bc [18432,32256) | fc [32256,46080) | gwtc appended by precomp2 at 46080
__global__ void k_prepw(const float* __restrict__ in_w, const float* __restrict__ out_w,
                        const float* __restrict__ bc_w, const float* __restrict__ fc_w,
                        short* __restrict__ wp){
  int i = blockIdx.x*256 + threadIdx.x;
  if (i >= 46080) return;
  float v;
  if (i < 13824){ int j=i/72, k=i%72; v = (k<64)? in_w[j*64+k] : 0.f; }
  else if (i < 18432){ int d=i-13824; int o=d/72, c=d%72; v = (c<64)? out_w[o*64+c] : 0.f; }
  else if (i < 32256){ int d=i-18432; int dt=d/4608, rr=d%4608, o=rr/72, c=rr%72; v = (c<64)? bc_w[o*192+c*3+dt] : 0.f; }
  else               { int d=i-32256; int dt=d/4608, rr=d%4608, o=rr/72, c=rr%72; v = (c<64)? fc_w[o*192+c*3+dt] : 0.f; }
  wp[i] = bf(v);
}

// ---------------- async weight staging (wave-linear global_load_lds, 16B chunks) ----------------
__device__ __forceinline__ void stage_async(short* dst, const short* src, int n16, int wv, int lane){
  for (int i0 = wv*64; i0 < n16; i0 += 256)
    GLOAD_LDS16(src + (size_t)(i0 + lane)*8, dst + (size_t)i0*8);
}

// conv as 3 row-shifted GEMMs over 72-stride LDS tiles
__device__ __forceinline__ void conv_gemm(const short* __restrict__ abuf, const short* __restrict__ wv,
                                          int arow0, int l15, int l4, f32x4 acc[4]){
  #pragma unroll
  for (int dt=0; dt<3; ++dt){
    #pragma unroll
    for (int kc=0; kc<2; ++kc){
      s16x8 a = *(const s16x8*)&abuf[(arow0 + l15 + dt)*72 + kc*32 + l4*8];
      #pragma unroll
      for (int nt=0; nt<4; ++nt){
        s16x8 b = *(const s16x8*)&wv[(dt*64 + nt*16 + l15)*72 + kc*32 + l4*8];
        acc[nt] = __builtin_amdgcn_mfma_f32_16x16x32_bf16(a, b, acc[nt], 0, 0, 0);
      }
    }
  }
}

// ---------------- fused temporal: coef->tc (K=18 GEMM) -> QKV -> MHA -> LN -> bc/fc ----------------
__global__ __launch_bounds__(256) void k_temporal3(
  const float* __restrict__ coef, int cst, const float* __restrict__ x,
  const short* __restrict__ wpack, const float* __restrict__ btc_g,
  const float* __restrict__ in_b, const float* __restrict__ out_b,
  const float* __restrict__ res_w, const float* __restrict__ res_b,
  const float* __restrict__ ln_g, const float* __restrict__ ln_b,
  const float* __restrict__ bc_b, const float* __restrict__ fc_b,
  float* __restrict__ out)
{
  __shared__ __align__(16) short wbuf[13824];   // qkv -> bc -> fc
  __shared__ __align__(16) short poolQ[4608];   // Q [64][72]
  __shared__ __align__(16) short poolK[4608];   // K [64][72]
  __shared__ __align__(16) short poolB[4608];   // tc -> O [64][72]
  __shared__ __align__(16) short pool1[4752];   // abuf [4][16][40] -> R [66][72]
  __shared__ __align__(16) short pool2[6144];   // gwtc [64][40] + btc(f32 @+2560) -> V^T [256][24]
  __shared__ __align__(16) short pbuf[1024];    // cbuf(f32, 384) -> P [64][16]

  const int tid = threadIdx.x;
  const int w = tid >> 6;
  const int lane = tid & 63;
  const int l15 = lane & 15, l4 = lane >> 4;
  const int ndb = blockIdx.x * 4;

  const f32x4 z4 = {0.f,0.f,0.f,0.f};
  s16x8 zf;
  #pragma unroll
  for (int j=0;j<8;++j) zf[j]=0;

  float* cbufF = (float*)pbuf;
  float* btcL  = (float*)(pool2 + 2560);

  // ---- P0a: coef -> cbuf
  if (tid < 96){
    int n = tid/24, c4 = tid%24;
    ((float4*)cbufF)[tid] = *(const float4*)(coef + (size_t)(ndb+n)*cst + c4*4);
  }
  __syncthreads();

  // ---- P0b: issue weight stages, copy btc, load out_w frags, build A
  stage_async(wbuf, wpack + 0, 1728, w, lane);        // qkv
  stage_async(pool2, wpack + 46080, 320, w, lane);    // gwtc
  ((float4*)btcL)[tid] = ((const float4*)btc_g)[tid]; // 1024 f32
  s16x8 owf[4][2];
  {
    const short* wout = wpack + 13824;
    #pragma unroll
    for (int nt=0; nt<4; ++nt){
      owf[nt][0] = *(const s16x8*)&wout[(nt*16+l15)*72 + 0  + l4*8];
      owf[nt][1] = *(const s16x8*)&wout[(nt*16+l15)*72 + 32 + l4*8];
    }
  }
  for (int i=tid; i<2048; i+=256){
    int n = i >> 9, rr = i & 511, t = rr >> 5, k = rr & 31;
    float v = 0.f;
    if (k < 18){
      int dt = (k >= 12) ? 2 : (k >= 6 ? 1 : 0);
      int j = k - dt*6;
      int u = t - 1 + dt;
      if (u >= 0 && u < 12) v = cbufF[n*96 + u*8 + j];
    }
    pool1[n*640 + t*40 + k] = bf(v);
  }
  __syncthreads();   // drains stages too

  // ---- P1: tc conv GEMM (K=32, 4 MFMAs) -> poolB (bf16, +bias table)
  {
    s16x8 a = *(const s16x8*)&pool1[w*640 + l15*40 + l4*8];
    f32x4 acc[4] = {z4,z4,z4,z4};
    #pragma unroll
    for (int nt=0; nt<4; ++nt){
      s16x8 b = *(const s16x8*)&pool2[(nt*16+l15)*40 + l4*8];
      acc[nt] = __builtin_amdgcn_mfma_f32_16x16x32_bf16(a, b, acc[nt], 0,0,0);
    }
    #pragma unroll
    for (int nt=0; nt<4; ++nt){
      #pragma unroll
      for (int r=0; r<4; ++r){
        int t = l4*4 + r;
        poolB[(w*16 + t)*72 + nt*16 + l15] = bf(acc[nt][r] + btcL[t*64 + nt*16 + l15]);
      }
    }
  }
  __syncthreads();

  // ---- P2: QKV GEMM -> Q, K, V^T(pool2)
  {
    s16x8 a0 = *(const s16x8*)&poolB[(w*16+l15)*72 + 0  + l4*8];
    s16x8 a1 = *(const s16x8*)&poolB[(w*16+l15)*72 + 32 + l4*8];
    #pragma unroll
    for (int grp=0; grp<3; ++grp){
      f32x4 acc[4] = {z4,z4,z4,z4};
      #pragma unroll
      for (int nt=0; nt<4; ++nt){
        s16x8 b0 = *(const s16x8*)&wbuf[((grp*4+nt)*16 + l15)*72 + 0  + l4*8];
        acc[nt] = __builtin_amdgcn_mfma_f32_16x16x32_bf16(a0, b0, acc[nt], 0,0,0);
        s16x8 b1 = *(const s16x8*)&wbuf[((grp*4+nt)*16 + l15)*72 + 32 + l4*8];
        acc[nt] = __builtin_amdgcn_mfma_f32_16x16x32_bf16(a1, b1, acc[nt], 0,0,0);
      }
      #pragma unroll
      for (int nt=0; nt<4; ++nt){
        float bb = in_b[(grp*4+nt)*16 + l15];
        if (grp==0){
          #pragma unroll
          for (int r=0;r<4;++r) poolQ[(w*16 + l4*4 + r)*72 + nt*16 + l15] = bf(acc[nt][r] + bb);
        } else if (grp==1){
          #pragma unroll
          for (int r=0;r<4;++r) poolK[(w*16 + l4*4 + r)*72 + nt*16 + l15] = bf(acc[nt][r] + bb);
        } else {  // V: h == nt, dh == l15 -> V^T rows [dh][t]
          s16x4 pk;
          pk.x=bf(acc[nt][0]+bb); pk.y=bf(acc[nt][1]+bb); pk.z=bf(acc[nt][2]+bb); pk.w=bf(acc[nt][3]+bb);
          *(s16x4*)&pool2[((w*4 + nt)*16 + l15)*24 + l4*4] = pk;
        }
      }
    }
  }
  __syncthreads();
  stage_async(wbuf, wpack + 18432, 1728, w, lane);   // bc (hidden behind P3+P4)

  // ---- P3: attention (single-pass softmax, no max)
  {
    #pragma unroll 1
    for (int h=0; h<4; ++h){
      s16x8 qa = zf, kb = zf;
      if (l4 < 2){
        qa = *(const s16x8*)&poolQ[(w*16 + l15)*72 + h*16 + l4*8];
        kb = *(const s16x8*)&poolK[(w*16 + l15)*72 + h*16 + l4*8];
      }
      f32x4 sc = __builtin_amdgcn_mfma_f32_16x16x32_bf16(qa, kb, z4, 0,0,0);  // col=kt, row=q
      float invz[4];
      #pragma unroll
      for (int r=0; r<4; ++r){
        float e = (l15 < 12) ? __expf(sc[r]*0.25f) : 0.f;
        float z = e;
        #pragma unroll
        for (int dd=1; dd<16; dd<<=1) z += __shfl_xor(z, dd);
        invz[r] = 1.f/z;
        pbuf[(w*16 + l4*4 + r)*16 + l15] = bf(e);
      }
      s16x8 pa = zf, vb = zf;
      if (l4 < 2){
        pa = *(const s16x8*)&pbuf[(w*16 + l15)*16 + l4*8];
        vb = *(const s16x8*)&pool2[((w*4 + h)*16 + l15)*24 + l4*8];
      }
      f32x4 ov = __builtin_amdgcn_mfma_f32_16x16x32_bf16(pa, vb, z4, 0,0,0);  // col=dh, row=q
      #pragma unroll
      for (int r=0; r<4; ++r)
        poolB[(w*16 + l4*4 + r)*72 + h*16 + l15] = bf(ov[r]*invz[r]);
    }
  }

  // ---- P4: out-proj (regs) + residual + relu + LN -> R(pool1)
  for (int i=lane; i<144; i+=64){
    int sel=i/36, cc=i%36;
    int u = (sel==0)?0:(12+sel);
    ((int*)pool1)[(w*16+u)*36 + cc] = 0;
  }
  if (w==3) for (int i=lane; i<72; i+=64) ((int*)pool1)[64*36 + i] = 0;
  {
    s16x8 a0 = *(const s16x8*)&poolB[(w*16+l15)*72 + 0  + l4*8];
    s16x8 a1 = *(const s16x8*)&poolB[(w*16+l15)*72 + 32 + l4*8];
    f32x4 acc[4] = {z4,z4,z4,z4};
    #pragma unroll
    for (int nt=0; nt<4; ++nt){
      acc[nt] = __builtin_amdgcn_mfma_f32_16x16x32_bf16(a0, owf[nt][0], acc[nt], 0,0,0);
      acc[nt] = __builtin_amdgcn_mfma_f32_16x16x32_bf16(a1, owf[nt][1], acc[nt], 0,0,0);
    }
    float xr[4];
    #pragma unroll
    for (int r=0; r<4; ++r){ int t=l4*4+r; xr[r] = (t<12) ? x[(size_t)(ndb+w)*12 + t] : 0.f; }
    float zr[4][4], sum[4]={0,0,0,0}, sq[4]={0,0,0,0};
    #pragma unroll
    for (int nt=0; nt<4; ++nt){
      int o = nt*16 + l15;
      float ob=out_b[o], rw=res_w[o], rb=res_b[o];
      #pragma unroll
      for (int r=0; r<4; ++r){
        float v = acc[nt][r] + ob + xr[r]*rw + rb;
        v = v>0.f ? v : 0.f;
        zr[nt][r]=v; sum[r]+=v; sq[r]+=v*v;
      }
    }
    #pragma unroll
    for (int r=0; r<4; ++r){
      #pragma unroll
      for (int dd=1; dd<16; dd<<=1){ sum[r]+=__shfl_xor(sum[r],dd); sq[r]+=__shfl_xor(sq[r],dd); }
    }
    if (l4 < 3){
      #pragma unroll
      for (int r=0; r<4; ++r){
        float mu = sum[r]*(1.f/64.f);
        float va = sq[r]*(1.f/64.f) - mu*mu;
        float iv = rsqrtf(fmaxf(va,0.f) + 1e-5f);
        #pragma unroll
        for (int nt=0; nt<4; ++nt){
          int o = nt*16 + l15;
          int t = l4*4 + r;
          pool1[(w*16 + t + 1)*72 + o] = bf((zr[nt][r]-mu)*iv*ln_g[o] + ln_b[o]);
        }
      }
    }
  }
  __syncthreads();   // drains bc stage; R complete

  // ---- P5: backcast conv GEMM -> out
  {
    f32x4 acc[4] = {z4,z4,z4,z4};
    conv_gemm(pool1, wbuf, w*16, l15, l4, acc);
    if (l4 < 3){
      #pragma unroll
      for (int nt=0; nt<4; ++nt){
        int o = nt*16 + l15; float bb = bc_b[o];
        float4 v; v.x=acc[nt][0]+bb; v.y=acc[nt][1]+bb; v.z=acc[nt][2]+bb; v.w=acc[nt][3]+bb;
        *(float4*)&out[(size_t)(ndb+w)*768 + o*12 + l4*4] = v;
      }
    }
  }
  __syncthreads();
  stage_async(wbuf, wpack + 32256, 1728, w, lane);   // fc
  __syncthreads();

  // ---- P6: forecast conv GEMM -> out
  {
    f32x4 acc[4] = {z4,z4,z4,z4};
    conv_gemm(pool1, wbuf, w*16, l15, l4, acc);
    if (l4 < 3){
      #pragma unroll
      for (int nt=0; nt<4; ++nt){
        int o = nt*16 + l15; float bb = fc_b[o];
        float4 v; v.x=acc[nt][0]+bb; v.y=acc[nt][1]+bb; v.z=acc[nt][2]+bb; v.w=acc[nt][3]+bb;
        *(float4*)&out[30720000 + (size_t)(ndb+w)*768 + o*12 + l4*4] = v;
      }
    }
  }
}

// ---------------- host ----------------
extern "C" void kernel_launch(void* const* d_in, const int* in_sizes, int n_in,
                              void* d_out, int out_size, void* d_ws, size_t ws_size,
                              hipStream_t stream){
  const float* x      = (const float*)d_in[0];
  const int*   ei     = (const int*)d_in[1];
  const float* cheb_w = (const float*)d_in[2];
  const float* cheb_b = (const float*)d_in[3];
  const float* gat_w  = (const float*)d_in[4];
  const float* att_src= (const float*)d_in[5];
  const float* att_dst= (const float*)d_in[6];
  const float* gat_b  = (const float*)d_in[7];
  const float* tc_w   = (const float*)d_in[8];
  const float* tc_b   = (const float*)d_in[9];
  const float* in_w   = (const float*)d_in[10];
  const float* in_b   = (const float*)d_in[11];
  const float* out_w  = (const float*)d_in[12];
  const float* out_b  = (const float*)d_in[13];
  const float* res_w  = (const float*)d_in[14];
  const float* res_b  = (const float*)d_in[15];
  const float* ln_g   = (const float*)d_in[16];
  const float* ln_b   = (const float*)d_in[17];
  const float* bc_w   = (const float*)d_in[18];
  const float* bc_b   = (const float*)d_in[19];
  const float* fc_w   = (const float*)d_in[20];
  const float* fc_b   = (const float*)d_in[21];
  float* out = (float*)d_out;

  char* w = (char*)d_ws;
  size_t off = 0;
  auto alloc = [&](size_t bytes)->void*{ void* p = w + off; off += (bytes + 255) & ~(size_t)255; return p; };
  int*   degcnt = (int*)alloc((size_t)BN*4);
  int*   cnt    = (int*)alloc((size_t)BN*4);
  int*   rowptr = (int*)alloc((size_t)(BN+1)*4);
  int*   cursor = (int*)alloc((size_t)BN*4);
  int*   esrc   = (int*)alloc((size_t)EE*4);
  float* ew     = (float*)alloc((size_t)EE*4);
  float* tx1    = (float*)alloc((size_t)BN*TT*4);
  float* tx2    = (float*)alloc((size_t)BN*TT*4);
  float* gwb    = (float*)alloc(1024*4);
  float* dis    = (float*)alloc((size_t)BN*4);
  short* wpack  = (short*)alloc((size_t)(46080+2560)*2);   // + gwtc region
  float* btc    = (float*)alloc(1024*4);

  // coef: 8 floats per (node,t). Normal: packed in ws (stride 96 floats/node).
  // Fallback: node-major slots inside the backcast half of d_out (stride 768) —
  // block b reads its 4 nodes' coef in P0 and overwrites that exact region in P5.
  size_t coefBytes = (size_t)BN*TT*8*4;
  float* coefp; int cst;
  if (off + coefBytes <= ws_size){ coefp = (float*)(w + off); off += coefBytes; cst = 96; }
  else { coefp = out; cst = 768; }

  hipMemsetAsync(degcnt, 0, (size_t)BN*4, stream);
  hipMemsetAsync(cnt,    0, (size_t)BN*4, stream);
  k_hist    <<<(EE+255)/256, 256, 0, stream>>>(ei, degcnt, cnt);
  k_dis     <<<(BN+255)/256, 256, 0, stream>>>(degcnt, dis);
  k_scan    <<<1, 1024, 0, stream>>>(cnt, rowptr, cursor);
  k_scatter <<<(EE+255)/256, 256, 0, stream>>>(ei, dis, cursor, esrc, ew);
  k_prop1v  <<<(BN*3+255)/256, 256, 0, stream>>>(x, rowptr, esrc, ew, tx1);
  k_prop2v  <<<(BN*3+255)/256, 256, 0, stream>>>(x, tx1, rowptr, esrc, ew, tx2);
  k_precomp <<<1, 128, 0, stream>>>(cheb_w, cheb_b, gat_w, att_src, att_dst, gwb);
  k_precomp2<<<1, 64, 0, stream>>>(gwb, tc_w, tc_b, gat_b, wpack + 46080, btc);
  k_prepw   <<<(46080+255)/256, 256, 0, stream>>>(in_w, out_w, bc_w, fc_w, wpack);
  k_gat3    <<<(BN*6+255)/256, 256, 0, stream>>>(x, tx1, tx2, rowptr, esrc, gwb, coefp, cst);
  k_temporal3<<<BN/4, 256, 0, stream>>>(coefp, cst, x, wpack, btc, in_b, out_b,
                                        res_w, res_b, ln_g, ln_b, bc_b, fc_b, out);
}

// Round 6
// 409.909 us; speedup vs baseline: 9.3384x; 1.0870x over previous
//
#include <hip/hip_runtime.h>

#define BN 40000
#define TT 12
#define EE 160000

typedef __attribute__((ext_vector_type(4))) float f32x4;
typedef __attribute__((ext_vector_type(4))) short s16x4;
typedef __attribute__((ext_vector_type(8))) short s16x8;

__device__ __forceinline__ float lrelu(float v){ return v > 0.f ? v : 0.2f*v; }

__device__ __forceinline__ short bf(float f){
  union { float f; unsigned u; } x; x.f = f;
  unsigned r = x.u + 0x7fffu + ((x.u >> 16) & 1u);
  return (short)(r >> 16);
}

#define GLOAD_LDS16(g, l) __builtin_amdgcn_global_load_lds( \
    (const __attribute__((address_space(1))) void*)(g), \
    (__attribute__((address_space(3))) void*)(l), 16, 0, 0)

// ---------------- graph preprocessing ----------------
__global__ void k_hist(const int* __restrict__ ei, int* __restrict__ degcnt, int* __restrict__ cnt){
  int e = blockIdx.x*256 + threadIdx.x;
  if (e < EE){
    atomicAdd(&degcnt[ei[e]], 1);      // src out-degree (ChebConv norm)
    atomicAdd(&cnt[ei[EE + e]], 1);    // dst in-degree (CSR)
  }
}

__global__ void k_scan(const int* __restrict__ cnt, int* __restrict__ rowptr, int* __restrict__ cursor){
  __shared__ int part[1024];
  int tid = threadIdx.x;
  const int CH = 40;
  int base = tid*CH;
  int s = 0;
  for (int j=0;j<CH;++j){ int idx=base+j; if (idx<BN) s += cnt[idx]; }
  part[tid] = s; __syncthreads();
  for (int off=1; off<1024; off<<=1){
    int v = (tid>=off)? part[tid-off] : 0;
    __syncthreads();
    part[tid] += v;
    __syncthreads();
  }
  int run = part[tid] - s;
  for (int j=0;j<CH;++j){ int idx=base+j; if (idx<BN){ rowptr[idx]=run; cursor[idx]=run; run += cnt[idx]; } }
  if (tid==1023) rowptr[BN] = part[1023];
}

__global__ void k_scatter(const int* __restrict__ ei, const int* __restrict__ degcnt,
                          int* __restrict__ cursor, int* __restrict__ esrc, float* __restrict__ ew){
  int e = blockIdx.x*256 + threadIdx.x;
  if (e < EE){
    int s = ei[e], d = ei[EE+e];
    int p = atomicAdd(&cursor[d], 1);
    esrc[p] = s;
    int ds_ = degcnt[s], dd_ = degcnt[d];
    float isd = ds_ > 0 ? rsqrtf((float)ds_) : 0.f;
    float idd = dd_ > 0 ? rsqrtf((float)dd_) : 0.f;
    ew[p] = -isd*idd;
  }
}

// ---------------- Cheb propagation, vectorized: thread = (node, t-quarter) ----------------
__global__ void k_prop1v(const float* __restrict__ x, const int* __restrict__ rowptr,
                         const int* __restrict__ esrc, const float* __restrict__ ew,
                         float* __restrict__ tx1){
  int i = blockIdx.x*256 + threadIdx.x;
  if (i >= BN*3) return;
  int d = i/3, q = i - d*3;
  int r0 = rowptr[d], r1 = rowptr[d+1];
  float4 a = {0.f,0.f,0.f,0.f};
  for (int p=r0;p<r1;++p){
    float wv = ew[p];
    float4 v = ((const float4*)x)[esrc[p]*3 + q];
    a.x += wv*v.x; a.y += wv*v.y; a.z += wv*v.z; a.w += wv*v.w;
  }
  ((float4*)tx1)[i] = a;
}

__global__ void k_prop2v(const float* __restrict__ x, const float* __restrict__ tx1,
                         const int* __restrict__ rowptr, const int* __restrict__ esrc,
                         const float* __restrict__ ew, float* __restrict__ tx2){
  int i = blockIdx.x*256 + threadIdx.x;
  if (i >= BN*3) return;
  int d = i/3, q = i - d*3;
  int r0 = rowptr[d], r1 = rowptr[d+1];
  float4 a = {0.f,0.f,0.f,0.f};
  for (int p=r0;p<r1;++p){
    float wv = ew[p];
    float4 v = ((const float4*)tx1)[esrc[p]*3 + q];
    a.x += wv*v.x; a.y += wv*v.y; a.z += wv*v.z; a.w += wv*v.w;
  }
  float4 xv = ((const float4*)x)[i];
  float4 o; o.x = 2.f*a.x - xv.x; o.y = 2.f*a.y - xv.y; o.z = 2.f*a.z - xv.z; o.w = 2.f*a.w - xv.w;
  ((float4*)tx2)[i] = o;
}

// ---------------- merged prep ----------------
// wp layout (shorts, row-major padded — round-3 layouts):
//   QKV [0,13824):      [j][72]        = in_w[j*64 + k], k<64 else 0
//   BC  [13824,27648):  [dt*64+o][72]  = bc_w[o*192 + c*3 + dt]
//   FC  [27648,41472):  [dt*64+o][72]  = fc_w[o*192 + c*3 + dt]
//   OUT [41472,46080):  [o][72]        = out_w[o*64 + c]
//   GWTC[46080,48640):  [o][40]        = fold(tc_w, G), zeros k>=18
__global__ void k_prep(const float* __restrict__ cheb_w, const float* __restrict__ cheb_b,
                       const float* __restrict__ gat_w, const float* __restrict__ att_src,
                       const float* __restrict__ att_dst, const float* __restrict__ gat_b,
                       const float* __restrict__ tc_w, const float* __restrict__ tc_b,
                       const float* __restrict__ in_w, const float* __restrict__ out_w,
                       const float* __restrict__ bc_w, const float* __restrict__ fc_w,
                       float* __restrict__ gwbuf, short* __restrict__ wp, float* __restrict__ btc){
  if (blockIdx.x == 0){
    __shared__ float sgw[384]; __shared__ float sgc[128];
    int hc = threadIdx.x;
    if (hc < 128){
      for (int k=0;k<3;++k){
        float a=0; for (int c=0;c<64;++c) a += cheb_w[k*64+c]*gat_w[hc*64+c];
        sgw[k*128+hc]=a; gwbuf[k*128+hc]=a;
      }
      float g=0; for (int c=0;c<64;++c) g += cheb_b[c]*gat_w[hc*64+c];
      sgc[hc]=g; gwbuf[384+hc]=g;
    }
    __syncthreads();
    if (hc<6){ int k=hc>>1, h=hc&1; float a=0,d=0;
      for (int c=0;c<64;++c){ float g=sgw[k*128+h*64+c]; a+=g*att_src[h*64+c]; d+=g*att_dst[h*64+c]; }
      gwbuf[512+hc]=a; gwbuf[518+hc]=d; }
    if (hc<2){ float a=0,d=0;
      for (int c=0;c<64;++c){ float g=sgc[hc*64+c]; a+=g*att_src[hc*64+c]; d+=g*att_dst[hc*64+c]; }
      gwbuf[524+hc]=a; gwbuf[526+hc]=d; }
    __syncthreads();
    if (hc < 64){
      int o = hc;
      short* gw2 = wp + 46080;
      float sbias[3];
      for (int dt=0; dt<3; ++dt){
        float s[6] = {0,0,0,0,0,0};
        float sb = 0.f;
        for (int c=0;c<64;++c){
          float wv = tc_w[o*192 + c*3 + dt];
          for (int j=0;j<3;++j){
            s[j]   += wv * sgw[j*128 + c];
            s[3+j] += wv * sgw[j*128 + 64 + c];
          }
          sb += wv * (gat_b[c] + 0.5f*(sgc[c] + sgc[64+c]));
        }
        for (int j=0;j<6;++j) gw2[o*40 + dt*6 + j] = bf(s[j]);
        sbias[dt] = sb;
      }
      for (int k=18;k<40;++k) gw2[o*40+k] = 0;
      for (int t=0;t<16;++t){
        float b = tc_b[o];
        if (t < 12){
          if (t > 0)  b += sbias[0];
          b += sbias[1];
          if (t < 11) b += sbias[2];
        }
        btc[t*64+o] = b;
      }
    }
  } else {
    int i = (blockIdx.x-1)*256 + threadIdx.x;
    if (i >= 46080) return;
    float v;
    if (i < 13824){ int j=i/72, k=i%72; v = (k<64)? in_w[j*64+k] : 0.f; }
    else if (i < 27648){ int d=i-13824; int dt=d/4608, rr=d%4608, o=rr/72, c=rr%72; v = (c<64)? bc_w[o*192+c*3+dt] : 0.f; }
    else if (i < 41472){ int d=i-27648; int dt=d/4608, rr=d%4608, o=rr/72, c=rr%72; v = (c<64)? fc_w[o*192+c*3+dt] : 0.f; }
    else               { int d=i-41472; int o=d/72, c=d%72; v = (c<64)? out_w[o*64+c] : 0.f; }
    wp[i] = bf(v);
  }
}

// ---------------- GAT: thread = (node, t-quarter, head); single-pass softmax + linearity ----------------
__global__ __launch_bounds__(256) void k_gat3(const float* __restrict__ x, const float* __restrict__ tx1,
     const float* __restrict__ tx2, const int* __restrict__ rowptr, const int* __restrict__ esrc,
     const float* __restrict__ gwbuf, float* __restrict__ coef, int cst){
  int i = blockIdx.x*256 + threadIdx.x;
  if (i >= BN*6) return;
  int d = i/6, r = i - d*6;
  int q = r >> 1, h = r & 1;

  float as0 = gwbuf[512+0+h], as1 = gwbuf[512+2+h], as2 = gwbuf[512+4+h];
  float ad0 = gwbuf[518+0+h], ad1 = gwbuf[518+2+h], ad2 = gwbuf[518+4+h];
  float asc = gwbuf[524+h],   adc = gwbuf[526+h];

  float4 t0 = ((const float4*)x)[d*3+q];
  float4 t1 = ((const float4*)tx1)[d*3+q];
  float4 t2 = ((const float4*)tx2)[d*3+q];
  float td0[4] = {t0.x,t0.y,t0.z,t0.w};
  float td1[4] = {t1.x,t1.y,t1.z,t1.w};
  float td2[4] = {t2.x,t2.y,t2.z,t2.w};

  float adh[4], S0[4], S1[4], S2[4], Z[4];
  #pragma unroll
  for (int t=0;t<4;++t){
    adh[t] = td0[t]*ad0 + td1[t]*ad1 + td2[t]*ad2 + adc;
    float es = lrelu(td0[t]*as0 + td1[t]*as1 + td2[t]*as2 + asc + adh[t]);
    float p = __expf(es);
    S0[t] = p*td0[t]; S1[t] = p*td1[t]; S2[t] = p*td2[t]; Z[t] = p;
  }
  int r0 = rowptr[d], r1 = rowptr[d+1];
  for (int p=r0;p<r1;++p){
    int s = esrc[p];
    float4 v0 = ((const float4*)x)[s*3+q];
    float4 v1 = ((const float4*)tx1)[s*3+q];
    float4 v2 = ((const float4*)tx2)[s*3+q];
    float s0[4] = {v0.x,v0.y,v0.z,v0.w};
    float s1[4] = {v1.x,v1.y,v1.z,v1.w};
    float s2[4] = {v2.x,v2.y,v2.z,v2.w};
    #pragma unroll
    for (int t=0;t<4;++t){
      float e = lrelu(s0[t]*as0 + s1[t]*as1 + s2[t]*as2 + asc + adh[t]);
      float pp = __expf(e);
      S0[t] += pp*s0[t]; S1[t] += pp*s1[t]; S2[t] += pp*s2[t]; Z[t] += pp;
    }
  }
  float* cw = coef + (size_t)d*cst + q*32;   // 4 t's x 8
  #pragma unroll
  for (int t=0;t<4;++t){
    float inv = 0.5f/Z[t];
    cw[t*8 + h*3 + 0] = S0[t]*inv;
    cw[t*8 + h*3 + 1] = S1[t]*inv;
    cw[t*8 + h*3 + 2] = S2[t]*inv;
  }
}

// ---------------- fused temporal: round-3 phase math, 8 nodes / 512-thread block, 1 barrier ----------------
// LDS: [0,41472) staged weights (qkv|bc|fc, row-major 72-padded); per node (4736 shorts):
//   +0 tcO/O [16][72] | +1152 Q [16][72] (R[18][72] aliased over Q + head of K)
//   | +2304 K [16][72] | +3456 Vt [64][16] (Ac [16][40] aliased) | +4480 P [16][16]
__global__ __launch_bounds__(512, 2) void k_temporal5(
  const float* __restrict__ coef, int cst, const float* __restrict__ x,
  const short* __restrict__ wp, const float* __restrict__ btc,
  const float* __restrict__ in_b, const float* __restrict__ out_b,
  const float* __restrict__ res_w, const float* __restrict__ res_b,
  const float* __restrict__ ln_g, const float* __restrict__ ln_b,
  const float* __restrict__ bc_b, const float* __restrict__ fc_b,
  float* __restrict__ out)
{
  __shared__ __align__(16) short lds[79360];   // 155 KiB

  const int tid = threadIdx.x;
  const int wv = tid >> 6;
  const int lane = tid & 63;
  const int l15 = lane & 15, l4 = lane >> 4;
  const int nd = blockIdx.x*8 + wv;

  short* nb  = lds + 41472 + wv*4736;
  short* tcO = nb;            // [16][72] : tc out, later attention O
  short* Q   = nb + 1152;     // [16][72]
  short* R   = nb + 1152;     // [18][72] alias over Q + first 2 rows of K
  short* K   = nb + 2304;     // [16][72]
  short* Vt  = nb + 3456;     // [64][16]
  short* Ac  = nb + 3456;     // [16][40] alias over Vt (dead before Vt written)
  short* Pb  = nb + 4480;     // [16][16]

  const f32x4 z4 = {0.f,0.f,0.f,0.f};
  s16x8 zf;
  #pragma unroll
  for (int j=0;j<8;++j) zf[j]=0;

  // ---- stage qkv+bc+fc weights: 5184 x 16B chunks, async
  for (int i0 = wv*64; i0 < 5184; i0 += 512)
    GLOAD_LDS16(wp + (size_t)(i0 + lane)*8, lds + (size_t)i0*8);

  // ---- A-build (own node): A[t][k], k=dt*6+j, zeros k>=18
  {
    int t = lane >> 2, l2 = lane & 3;
    const float* cb = coef + (size_t)nd*cst;
    s16x8 ap;
    #pragma unroll
    for (int e=0; e<8; ++e){
      int k = l2*8 + e;
      int dt = (k>=12) ? 2 : ((k>=6) ? 1 : 0);
      int j = k - dt*6;
      int u = t - 1 + dt;
      float v = 0.f;
      if (k < 18 && u >= 0 && u < 12) v = cb[u*8 + j];
      ap[e] = bf(v);
    }
    *(s16x8*)&Ac[t*40 + l2*8] = ap;
  }

  // ---- P1: tc GEMM (A = coef rows, B = gwtc global row-major) -> tcO[t][o]
  {
    s16x8 a = *(const s16x8*)&Ac[l15*40 + l4*8];
    #pragma unroll
    for (int nt=0; nt<4; ++nt){
      s16x8 b = *(const s16x8*)&wp[46080 + (nt*16+l15)*40 + l4*8];
      f32x4 acc = __builtin_amdgcn_mfma_f32_16x16x32_bf16(a, b, z4, 0,0,0);  // row=t, col=o
      #pragma unroll
      for (int r=0; r<4; ++r){
        int t = l4*4 + r;
        tcO[t*72 + nt*16 + l15] = bf(acc[r] + btc[t*64 + nt*16 + l15]);
      }
    }
  }

  __syncthreads();   // drains weight DMA; all phases below are per-wave independent

  // ---- P2: QKV GEMM -> Q[t][j], K[t][j], Vt[dh][t]
  {
    s16x8 a0 = *(const s16x8*)&tcO[l15*72 +  0 + l4*8];
    s16x8 a1 = *(const s16x8*)&tcO[l15*72 + 32 + l4*8];
    #pragma unroll
    for (int grp=0; grp<3; ++grp){
      f32x4 acc[4];
      #pragma unroll
      for (int nt=0; nt<4; ++nt){
        s16x8 b0 = *(const s16x8*)&lds[((grp*4+nt)*16 + l15)*72 +  0 + l4*8];
        acc[nt] = __builtin_amdgcn_mfma_f32_16x16x32_bf16(a0, b0, z4, 0,0,0);
        s16x8 b1 = *(const s16x8*)&lds[((grp*4+nt)*16 + l15)*72 + 32 + l4*8];
        acc[nt] = __builtin_amdgcn_mfma_f32_16x16x32_bf16(a1, b1, acc[nt], 0,0,0);
      }
      #pragma unroll
      for (int nt=0; nt<4; ++nt){
        float bb = in_b[(grp*4+nt)*16 + l15];
        if (grp==0){
          #pragma unroll
          for (int r=0;r<4;++r) Q[(l4*4 + r)*72 + nt*16 + l15] = bf(acc[nt][r] + bb);
        } else if (grp==1){
          #pragma unroll
          for (int r=0;r<4;++r) K[(l4*4 + r)*72 + nt*16 + l15] = bf(acc[nt][r] + bb);
        } else {  // V: dh = nt*16+l15 (col), t = l4*4+r (row) -> Vt[dh][t] packed
          s16x4 pk;
          pk[0]=bf(acc[nt][0]+bb); pk[1]=bf(acc[nt][1]+bb);
          pk[2]=bf(acc[nt][2]+bb); pk[3]=bf(acc[nt][3]+bb);
          *(s16x4*)&Vt[(nt*16 + l15)*16 + l4*4] = pk;
        }
      }
    }
  }

  // ---- P3: attention (round-3 orientation: row=q, col=kt; single-pass softmax)
  {
    #pragma unroll 1
    for (int h=0; h<4; ++h){
      s16x8 qa = zf, kb = zf;
      if (l4 < 2){
        qa = *(const s16x8*)&Q[l15*72 + h*16 + l4*8];
        kb = *(const s16x8*)&K[l15*72 + h*16 + l4*8];
      }
      f32x4 sc = __builtin_amdgcn_mfma_f32_16x16x32_bf16(qa, kb, z4, 0,0,0);  // row=q, col=kt=l15
      float invz[4];
      #pragma unroll
      for (int r=0; r<4; ++r){
        float e = (l15 < 12) ? __expf(sc[r]*0.25f) : 0.f;
        float z = e;
        #pragma unroll
        for (int dd=1; dd<16; dd<<=1) z += __shfl_xor(z, dd);
        invz[r] = 1.f/z;
        Pb[(l4*4 + r)*16 + l15] = bf(e);     // P[q][kt]
      }
      s16x8 pa = zf, vb = zf;
      if (l4 < 2){
        pa = *(const s16x8*)&Pb[l15*16 + l4*8];
        vb = *(const s16x8*)&Vt[(h*16 + l15)*16 + l4*8];
      }
      f32x4 ov = __builtin_amdgcn_mfma_f32_16x16x32_bf16(pa, vb, z4, 0,0,0);  // row=q, col=dh
      #pragma unroll
      for (int r=0; r<4; ++r)
        tcO[(l4*4 + r)*72 + h*16 + l15] = bf(ov[r]*invz[r]);                  // O[t=q][j]
    }
  }

  // ---- P4: out-proj + residual + relu + LN -> R[u][o] (u=t+1)
  {
    // zero R pad rows {0,13,14,15,16,17} (Q/K head dead)
    s16x4 zz; zz[0]=0; zz[1]=0; zz[2]=0; zz[3]=0;
    for (int i=lane; i<108; i+=64){
      int rr = i/18, cc = i%18;
      int row = (rr==0) ? 0 : (12 + rr);
      *(s16x4*)&R[row*72 + cc*4] = zz;
    }
    s16x8 a0 = *(const s16x8*)&tcO[l15*72 +  0 + l4*8];
    s16x8 a1 = *(const s16x8*)&tcO[l15*72 + 32 + l4*8];
    f32x4 acc[4];
    #pragma unroll
    for (int nt=0; nt<4; ++nt){
      s16x8 w0 = *(const s16x8*)&wp[41472 + (nt*16+l15)*72 +  0 + l4*8];
      acc[nt] = __builtin_amdgcn_mfma_f32_16x16x32_bf16(a0, w0, z4, 0,0,0);
      s16x8 w1 = *(const s16x8*)&wp[41472 + (nt*16+l15)*72 + 32 + l4*8];
      acc[nt] = __builtin_amdgcn_mfma_f32_16x16x32_bf16(a1, w1, acc[nt], 0,0,0); // row=t, col=o
    }
    float xr[4];
    #pragma unroll
    for (int r=0; r<4; ++r){ int t=l4*4+r; xr[r] = (t<12) ? x[(size_t)nd*12 + t] : 0.f; }
    float zr[4][4], sum[4]={0,0,0,0}, sq[4]={0,0,0,0};
    #pragma unroll
    for (int nt=0; nt<4; ++nt){
      int o = nt*16 + l15;
      float ob=out_b[o], rw=res_w[o], rb=res_b[o];
      #pragma unroll
      for (int r=0; r<4; ++r){
        float v = acc[nt][r] + ob + xr[r]*rw + rb;
        v = v>0.f ? v : 0.f;
        zr[nt][r]=v; sum[r]+=v; sq[r]+=v*v;
      }
    }
    #pragma unroll
    for (int r=0; r<4; ++r){
      #pragma unroll
      for (int dd=1; dd<16; dd<<=1){ sum[r]+=__shfl_xor(sum[r],dd); sq[r]+=__shfl_xor(sq[r],dd); }
    }
    if (l4 < 3){
      #pragma unroll
      for (int r=0; r<4; ++r){
        float mu = sum[r]*(1.f/64.f);
        float va = sq[r]*(1.f/64.f) - mu*mu;
        float iv = rsqrtf(fmaxf(va,0.f) + 1e-5f);
        #pragma unroll
        for (int nt=0; nt<4; ++nt){
          int o = nt*16 + l15;
          int t = l4*4 + r;
          R[(t + 1)*72 + o] = bf((zr[nt][r]-mu)*iv*ln_g[o] + ln_b[o]);
        }
      }
    }
  }

  // ---- P5+P6 fused: backcast+forecast convs (A = R rows, B = staged frags)
  {
    f32x4 aB[4] = {z4,z4,z4,z4};
    f32x4 aF[4] = {z4,z4,z4,z4};
    #pragma unroll
    for (int dt=0; dt<3; ++dt){
      #pragma unroll
      for (int kc=0; kc<2; ++kc){
        s16x8 ar = *(const s16x8*)&R[(l15 + dt)*72 + kc*32 + l4*8];
        #pragma unroll
        for (int nt=0; nt<4; ++nt){
          s16x8 wb = *(const s16x8*)&lds[13824 + (dt*64 + nt*16 + l15)*72 + kc*32 + l4*8];
          aB[nt] = __builtin_amdgcn_mfma_f32_16x16x32_bf16(ar, wb, aB[nt], 0,0,0);
          s16x8 wf = *(const s16x8*)&lds[27648 + (dt*64 + nt*16 + l15)*72 + kc*32 + l4*8];
          aF[nt] = __builtin_amdgcn_mfma_f32_16x16x32_bf16(ar, wf, aF[nt], 0,0,0);
        }
      }
    }
    if (l4 < 3){
      #pragma unroll
      for (int nt=0; nt<4; ++nt){
        int o = nt*16 + l15;
        float bb = bc_b[o], fb = fc_b[o];
        float4 v; v.x=aB[nt][0]+bb; v.y=aB[nt][1]+bb; v.z=aB[nt][2]+bb; v.w=aB[nt][3]+bb;
        *(float4*)&out[(size_t)nd*768 + o*12 + l4*4] = v;
        float4 f; f.x=aF[nt][0]+fb; f.y=aF[nt][1]+fb; f.z=aF[nt][2]+fb; f.w=aF[nt][3]+fb;
        *(float4*)&out[30720000 + (size_t)nd*768 + o*12 + l4*4] = f;
      }
    }
  }
}

// ---------------- host ----------------
extern "C" void kernel_launch(void* const* d_in, const int* in_sizes, int n_in,
                              void* d_out, int out_size, void* d_ws, size_t ws_size,
                              hipStream_t stream){
  const float* x      = (const float*)d_in[0];
  const int*   ei     = (const int*)d_in[1];
  const float* cheb_w = (const float*)d_in[2];
  const float* cheb_b = (const float*)d_in[3];
  const float* gat_w  = (const float*)d_in[4];
  const float* att_src= (const float*)d_in[5];
  const float* att_dst= (const float*)d_in[6];
  const float* gat_b  = (const float*)d_in[7];
  const float* tc_w   = (const float*)d_in[8];
  const float* tc_b   = (const float*)d_in[9];
  const float* in_w   = (const float*)d_in[10];
  const float* in_b   = (const float*)d_in[11];
  const float* out_w  = (const float*)d_in[12];
  const float* out_b  = (const float*)d_in[13];
  const float* res_w  = (const float*)d_in[14];
  const float* res_b  = (const float*)d_in[15];
  const float* ln_g   = (const float*)d_in[16];
  const float* ln_b   = (const float*)d_in[17];
  const float* bc_w   = (const float*)d_in[18];
  const float* bc_b   = (const float*)d_in[19];
  const float* fc_w   = (const float*)d_in[20];
  const float* fc_b   = (const float*)d_in[21];
  float* out = (float*)d_out;

  char* w = (char*)d_ws;
  size_t off = 0;
  auto alloc = [&](size_t bytes)->void*{ void* p = w + off; off += (bytes + 255) & ~(size_t)255; return p; };
  int*   cnt2   = (int*)alloc((size_t)2*BN*4);     // degcnt | cnt (one memset)
  int*   degcnt = cnt2;
  int*   cnt    = cnt2 + BN;
  int*   rowptr = (int*)alloc((size_t)(BN+1)*4);
  int*   cursor = (int*)alloc((size_t)BN*4);
  int*   esrc   = (int*)alloc((size_t)EE*4);
  float* ew     = (float*)alloc((size_t)EE*4);
  float* tx1    = (float*)alloc((size_t)BN*TT*4);
  float* tx2    = (float*)alloc((size_t)BN*TT*4);
  float* gwb    = (float*)alloc(1024*4);
  short* wpack  = (short*)alloc((size_t)48640*2);
  float* btc    = (float*)alloc(1024*4);

  // coef: 8 floats per (node,t). Normal: packed in ws (stride 96 floats/node).
  // Fallback: node-major slots in the backcast half of d_out (stride 768) —
  // each wave reads its node's coef (A-build) before overwriting that region (P5).
  size_t coefBytes = (size_t)BN*TT*8*4;
  float* coefp; int cst;
  if (off + coefBytes <= ws_size){ coefp = (float*)(w + off); off += coefBytes; cst = 96; }
  else { coefp = out; cst = 768; }

  hipMemsetAsync(cnt2, 0, (size_t)2*BN*4, stream);
  k_hist    <<<(EE+255)/256, 256, 0, stream>>>(ei, degcnt, cnt);
  k_scan    <<<1, 1024, 0, stream>>>(cnt, rowptr, cursor);
  k_scatter <<<(EE+255)/256, 256, 0, stream>>>(ei, degcnt, cursor, esrc, ew);
  k_prop1v  <<<(BN*3+255)/256, 256, 0, stream>>>(x, rowptr, esrc, ew, tx1);
  k_prop2v  <<<(BN*3+255)/256, 256, 0, stream>>>(x, tx1, rowptr, esrc, ew, tx2);
  k_prep    <<<181, 256, 0, stream>>>(cheb_w, cheb_b, gat_w, att_src, att_dst, gat_b,
                                      tc_w, tc_b, in_w, out_w, bc_w, fc_w, gwb, wpack, btc);
  k_gat3    <<<(BN*6+255)/256, 256, 0, stream>>>(x, tx1, tx2, rowptr, esrc, gwb, coefp, cst);
  k_temporal5<<<BN/8, 512, 0, stream>>>(coefp, cst, x, wpack, btc, in_b, out_b,
                                        res_w, res_b, ln_g, ln_b, bc_b, fc_b, out);
}

// Round 7
// 403.450 us; speedup vs baseline: 9.4879x; 1.0160x over previous
//
#include <hip/hip_runtime.h>

#define BN 40000
#define TT 12
#define EE 160000

typedef __attribute__((ext_vector_type(4))) float f32x4;
typedef __attribute__((ext_vector_type(4))) short s16x4;
typedef __attribute__((ext_vector_type(8))) short s16x8;

__device__ __forceinline__ float lrelu(float v){ return v > 0.f ? v : 0.2f*v; }

__device__ __forceinline__ short bf(float f){
  union { float f; unsigned u; } x; x.f = f;
  unsigned r = x.u + 0x7fffu + ((x.u >> 16) & 1u);
  return (short)(r >> 16);
}

#define GLOAD_LDS16(g, l) __builtin_amdgcn_global_load_lds( \
    (const __attribute__((address_space(1))) void*)(g), \
    (__attribute__((address_space(3))) void*)(l), 16, 0, 0)

// ---------------- merged hist + prep ----------------
// wp layout (row-major canonical, round-5):
//   QKV1 0      [j][72]       13824
//   BC1  13824  [dt*64+o][72] 13824
//   FC1  27648  [dt*64+o][72] 13824
//   OUT1 41472  [o][72]        4608
//   GWTC 46080  [o][40]        2560
__global__ void k_histprep(const int* __restrict__ ei, int* __restrict__ degcnt, int* __restrict__ cnt,
                       const float* __restrict__ cheb_w, const float* __restrict__ cheb_b,
                       const float* __restrict__ gat_w, const float* __restrict__ att_src,
                       const float* __restrict__ att_dst, const float* __restrict__ gat_b,
                       const float* __restrict__ tc_w, const float* __restrict__ tc_b,
                       const float* __restrict__ in_w, const float* __restrict__ out_w,
                       const float* __restrict__ bc_w, const float* __restrict__ fc_w,
                       float* __restrict__ gwbuf, short* __restrict__ wp, float* __restrict__ btc){
  if (blockIdx.x < 625){
    int e = blockIdx.x*256 + threadIdx.x;
    if (e < EE){
      atomicAdd(&degcnt[ei[e]], 1);
      atomicAdd(&cnt[ei[EE + e]], 1);
    }
    return;
  }
  if (blockIdx.x == 625){
    __shared__ float sgw[384]; __shared__ float sgc[128];
    int hc = threadIdx.x;
    if (hc < 128){
      for (int k=0;k<3;++k){
        float a=0; for (int c=0;c<64;++c) a += cheb_w[k*64+c]*gat_w[hc*64+c];
        sgw[k*128+hc]=a; gwbuf[k*128+hc]=a;
      }
      float g=0; for (int c=0;c<64;++c) g += cheb_b[c]*gat_w[hc*64+c];
      sgc[hc]=g; gwbuf[384+hc]=g;
    }
    __syncthreads();
    if (hc<6){ int k=hc>>1, h=hc&1; float a=0,d=0;
      for (int c=0;c<64;++c){ float g=sgw[k*128+h*64+c]; a+=g*att_src[h*64+c]; d+=g*att_dst[h*64+c]; }
      gwbuf[512+hc]=a; gwbuf[518+hc]=d; }
    if (hc<2){ float a=0,d=0;
      for (int c=0;c<64;++c){ float g=sgc[hc*64+c]; a+=g*att_src[hc*64+c]; d+=g*att_dst[hc*64+c]; }
      gwbuf[524+hc]=a; gwbuf[526+hc]=d; }
    __syncthreads();
    if (hc < 64){
      int o = hc;
      short* gw2 = wp + 46080;
      float sbias[3];
      for (int dt=0; dt<3; ++dt){
        float s[6] = {0,0,0,0,0,0};
        float sb = 0.f;
        for (int c=0;c<64;++c){
          float wv = tc_w[o*192 + c*3 + dt];
          for (int j=0;j<3;++j){
            s[j]   += wv * sgw[j*128 + c];
            s[3+j] += wv * sgw[j*128 + 64 + c];
          }
          sb += wv * (gat_b[c] + 0.5f*(sgc[c] + sgc[64+c]));
        }
        for (int j=0;j<6;++j) gw2[o*40 + dt*6 + j] = bf(s[j]);
        sbias[dt] = sb;
      }
      for (int k=18;k<40;++k) gw2[o*40+k] = 0;
      for (int t=0;t<16;++t){
        float b = tc_b[o];
        if (t < 12){
          if (t > 0)  b += sbias[0];
          b += sbias[1];
          if (t < 11) b += sbias[2];
        }
        btc[t*64+o] = b;
      }
    }
    return;
  }
  int i = (blockIdx.x-626)*256 + threadIdx.x;
  if (i >= 46080) return;
  float v;
  if (i < 13824){ int j=i/72, k=i%72; v = (k<64)? in_w[j*64+k] : 0.f; }
  else if (i < 27648){ int d=i-13824; int dt=d/4608, rr=d%4608, o=rr/72, c=rr%72; v = (c<64)? bc_w[o*192+c*3+dt] : 0.f; }
  else if (i < 41472){ int d=i-27648; int dt=d/4608, rr=d%4608, o=rr/72, c=rr%72; v = (c<64)? fc_w[o*192+c*3+dt] : 0.f; }
  else               { int d=i-41472; int o=d/72, c=d%72; v = (c<64)? out_w[o*64+c] : 0.f; }
  wp[i] = bf(v);
}

// ---------------- repack: row-major wp -> lane-major wp2 (content-identical by construction) ----------------
// wp2 frag ids f2: QKV 0..23 (grp*8+nt*2+kc) | OUT 24..31 (24+mt*2+kc) |
//               BC 32..55 (32+dt*8+kc*4+nt) | FC 56..79. wp2[(f2*64+lane)*8+e]
__global__ void k_repack(const short* __restrict__ wp, short* __restrict__ wp2){
  int i = blockIdx.x*256 + threadIdx.x;
  if (i >= 40960) return;
  int f2 = i >> 9, lane = (i >> 3) & 63, e = i & 7;
  int l15 = lane & 15, l4 = lane >> 4;
  int src;
  if (f2 < 24){
    int grp = f2 >> 3, nt = (f2 >> 1) & 3, kc = f2 & 1;
    src = 0     + ((grp*4+nt)*16 + l15)*72 + kc*32 + l4*8 + e;
  } else if (f2 < 32){
    int g = f2 - 24; int mt = g >> 1, kc = g & 1;
    src = 41472 + (mt*16 + l15)*72 + kc*32 + l4*8 + e;
  } else if (f2 < 56){
    int g = f2 - 32; int dt = g >> 3, kc = (g >> 2) & 1, nt = g & 3;
    src = 13824 + (dt*64 + nt*16 + l15)*72 + kc*32 + l4*8 + e;
  } else {
    int g = f2 - 56; int dt = g >> 3, kc = (g >> 2) & 1, nt = g & 3;
    src = 27648 + (dt*64 + nt*16 + l15)*72 + kc*32 + l4*8 + e;
  }
  wp2[i] = wp[src];
}

__global__ void k_scan(const int* __restrict__ cnt, int* __restrict__ rowptr, int* __restrict__ cursor){
  __shared__ int part[1024];
  int tid = threadIdx.x;
  const int CH = 40;
  int base = tid*CH;
  int s = 0;
  for (int j=0;j<CH;++j){ int idx=base+j; if (idx<BN) s += cnt[idx]; }
  part[tid] = s; __syncthreads();
  for (int off=1; off<1024; off<<=1){
    int v = (tid>=off)? part[tid-off] : 0;
    __syncthreads();
    part[tid] += v;
    __syncthreads();
  }
  int run = part[tid] - s;
  for (int j=0;j<CH;++j){ int idx=base+j; if (idx<BN){ rowptr[idx]=run; cursor[idx]=run; run += cnt[idx]; } }
  if (tid==1023) rowptr[BN] = part[1023];
}

__global__ void k_scatter(const int* __restrict__ ei, const int* __restrict__ degcnt,
                          int* __restrict__ cursor, int* __restrict__ esrc, float* __restrict__ ew){
  int e = blockIdx.x*256 + threadIdx.x;
  if (e < EE){
    int s = ei[e], d = ei[EE+e];
    int p = atomicAdd(&cursor[d], 1);
    esrc[p] = s;
    int ds_ = degcnt[s], dd_ = degcnt[d];
    float isd = ds_ > 0 ? rsqrtf((float)ds_) : 0.f;
    float idd = dd_ > 0 ? rsqrtf((float)dd_) : 0.f;
    ew[p] = -isd*idd;
  }
}

// ---------------- Cheb propagation ----------------
__global__ void k_prop1v(const float* __restrict__ x, const int* __restrict__ rowptr,
                         const int* __restrict__ esrc, const float* __restrict__ ew,
                         float* __restrict__ tx1){
  int i = blockIdx.x*256 + threadIdx.x;
  if (i >= BN*3) return;
  int d = i/3, q = i - d*3;
  int r0 = rowptr[d], r1 = rowptr[d+1];
  float4 a = {0.f,0.f,0.f,0.f};
  for (int p=r0;p<r1;++p){
    float wv = ew[p];
    float4 v = ((const float4*)x)[esrc[p]*3 + q];
    a.x += wv*v.x; a.y += wv*v.y; a.z += wv*v.z; a.w += wv*v.w;
  }
  ((float4*)tx1)[i] = a;
}

__global__ void k_prop2v(const float* __restrict__ x, const float* __restrict__ tx1,
                         const int* __restrict__ rowptr, const int* __restrict__ esrc,
                         const float* __restrict__ ew, float* __restrict__ tx2){
  int i = blockIdx.x*256 + threadIdx.x;
  if (i >= BN*3) return;
  int d = i/3, q = i - d*3;
  int r0 = rowptr[d], r1 = rowptr[d+1];
  float4 a = {0.f,0.f,0.f,0.f};
  for (int p=r0;p<r1;++p){
    float wv = ew[p];
    float4 v = ((const float4*)tx1)[esrc[p]*3 + q];
    a.x += wv*v.x; a.y += wv*v.y; a.z += wv*v.z; a.w += wv*v.w;
  }
  float4 xv = ((const float4*)x)[i];
  float4 o; o.x = 2.f*a.x - xv.x; o.y = 2.f*a.y - xv.y; o.z = 2.f*a.z - xv.z; o.w = 2.f*a.w - xv.w;
  ((float4*)tx2)[i] = o;
}

// ---------------- GAT: thread = (node, t-quarter), BOTH heads; single-pass softmax + linearity ----------------
__global__ __launch_bounds__(256) void k_gat4(const float* __restrict__ x, const float* __restrict__ tx1,
     const float* __restrict__ tx2, const int* __restrict__ rowptr, const int* __restrict__ esrc,
     const float* __restrict__ gwbuf, float* __restrict__ coef, int cst){
  int i = blockIdx.x*256 + threadIdx.x;
  if (i >= BN*3) return;
  int d = i/3, q = i - d*3;

  float as[2][3], ad[2][3], asc[2], adc[2];
  #pragma unroll
  for (int h=0;h<2;++h){
    #pragma unroll
    for (int k=0;k<3;++k){ as[h][k] = gwbuf[512+2*k+h]; ad[h][k] = gwbuf[518+2*k+h]; }
    asc[h] = gwbuf[524+h]; adc[h] = gwbuf[526+h];
  }

  float4 t0 = ((const float4*)x)[d*3+q];
  float4 t1 = ((const float4*)tx1)[d*3+q];
  float4 t2 = ((const float4*)tx2)[d*3+q];
  float td0[4] = {t0.x,t0.y,t0.z,t0.w};
  float td1[4] = {t1.x,t1.y,t1.z,t1.w};
  float td2[4] = {t2.x,t2.y,t2.z,t2.w};

  float adh[2][4], S0[2][4], S1[2][4], S2[2][4], Z[2][4];
  #pragma unroll
  for (int h=0;h<2;++h){
    #pragma unroll
    for (int t=0;t<4;++t){
      adh[h][t] = td0[t]*ad[h][0] + td1[t]*ad[h][1] + td2[t]*ad[h][2] + adc[h];
      float es = lrelu(td0[t]*as[h][0] + td1[t]*as[h][1] + td2[t]*as[h][2] + asc[h] + adh[h][t]);
      float p = __expf(es);
      S0[h][t] = p*td0[t]; S1[h][t] = p*td1[t]; S2[h][t] = p*td2[t]; Z[h][t] = p;
    }
  }
  int r0 = rowptr[d], r1 = rowptr[d+1];
  for (int p=r0;p<r1;++p){
    int s = esrc[p];
    float4 v0 = ((const float4*)x)[s*3+q];
    float4 v1 = ((const float4*)tx1)[s*3+q];
    float4 v2 = ((const float4*)tx2)[s*3+q];
    float s0[4] = {v0.x,v0.y,v0.z,v0.w};
    float s1[4] = {v1.x,v1.y,v1.z,v1.w};
    float s2[4] = {v2.x,v2.y,v2.z,v2.w};
    #pragma unroll
    for (int h=0;h<2;++h){
      #pragma unroll
      for (int t=0;t<4;++t){
        float e = lrelu(s0[t]*as[h][0] + s1[t]*as[h][1] + s2[t]*as[h][2] + asc[h] + adh[h][t]);
        float pp = __expf(e);
        S0[h][t] += pp*s0[t]; S1[h][t] += pp*s1[t]; S2[h][t] += pp*s2[t]; Z[h][t] += pp;
      }
    }
  }
  float* cw = coef + (size_t)d*cst + q*32;
  #pragma unroll
  for (int t=0;t<4;++t){
    float inv0 = 0.5f/Z[0][t], inv1 = 0.5f/Z[1][t];
    float4 w4; w4.x = S0[0][t]*inv0; w4.y = S1[0][t]*inv0; w4.z = S2[0][t]*inv0; w4.w = S0[1][t]*inv1;
    *(float4*)(cw + t*8) = w4;
    float2 w2; w2.x = S1[1][t]*inv1; w2.y = S2[1][t]*inv1;
    *(float2*)(cw + t*8 + 4) = w2;
  }
}

// ---------------- fused temporal: 14 nodes / 896-thread block, 146 KB LDS, 1 barrier ----------------
// LDS: [0,12288) bc frags | [12288,24576) fc frags | per node (3584 shorts):
//   +0 tcO->Q->O [16][72] | +1152 Ac[16][40] -> K[16][72] -> R[18][72]
//   +2304 Vt[64][16] (R rows 16,17 spill here after Vt dead) | +3328 Pb[16][16]
__global__ __launch_bounds__(896, 1) void k_temporal6(
  const float* __restrict__ coef, int cst, const float* __restrict__ x,
  const short* __restrict__ wp, const short* __restrict__ wp2, const float* __restrict__ btc,
  const float* __restrict__ in_b, const float* __restrict__ out_b,
  const float* __restrict__ res_w, const float* __restrict__ res_b,
  const float* __restrict__ ln_g, const float* __restrict__ ln_b,
  const float* __restrict__ bc_b, const float* __restrict__ fc_b,
  float* __restrict__ out)
{
  __shared__ __align__(16) short lds[74752];   // 146 KiB

  const int tid = threadIdx.x;
  const int wv = tid >> 6;
  const int lane = tid & 63;
  const int l15 = lane & 15, l4 = lane >> 4;
  const int nd = blockIdx.x*14 + wv;

  short* nb  = lds + 24576 + wv*3584;
  short* tcO = nb;            // tc out -> Q -> O
  short* Ac  = nb + 1152;    // A coef tile
  short* K   = nb + 1152;    // over Ac (Ac dead after P1)
  short* R   = nb + 1152;    // [18][72] over K + head of Vt (both dead after P3)
  short* Vt  = nb + 2304;    // [64][16]
  short* Pb  = nb + 3328;    // [16][16]

  const f32x4 z4 = {0.f,0.f,0.f,0.f};
  s16x8 zf;
  #pragma unroll
  for (int j=0;j<8;++j) zf[j]=0;

  // ---- stage bc+fc frags (3072 x 16B), async; drained by the barrier before P5
  for (int i0 = wv*64; i0 < 3072; i0 += 896)
    GLOAD_LDS16(wp2 + 16384 + (size_t)(i0 + lane)*8, lds + (size_t)i0*8);

  if (nd < BN){
    // ---- A-build: A[t][k], k=dt*6+j, zeros k>=18
    {
      int t = lane >> 2, l2 = lane & 3;
      const float* cb = coef + (size_t)nd*cst;
      s16x8 ap;
      #pragma unroll
      for (int e=0; e<8; ++e){
        int k = l2*8 + e;
        int dt = (k>=12) ? 2 : ((k>=6) ? 1 : 0);
        int j = k - dt*6;
        int u = t - 1 + dt;
        float v = 0.f;
        if (k < 18 && u >= 0 && u < 12) v = cb[u*8 + j];
        ap[e] = bf(v);
      }
      *(s16x8*)&Ac[t*40 + l2*8] = ap;
    }

    // ---- P1: tc GEMM (A = coef rows, B = gwtc global row-major) -> tcO[t][o]
    {
      s16x8 a = *(const s16x8*)&Ac[l15*40 + l4*8];
      #pragma unroll
      for (int nt=0; nt<4; ++nt){
        s16x8 b = *(const s16x8*)&wp[46080 + (nt*16+l15)*40 + l4*8];
        f32x4 acc = __builtin_amdgcn_mfma_f32_16x16x32_bf16(a, b, z4, 0,0,0);  // row=t, col=o
        #pragma unroll
        for (int r=0; r<4; ++r){
          int t = l4*4 + r;
          tcO[t*72 + nt*16 + l15] = bf(acc[r] + btc[t*64 + nt*16 + l15]);
        }
      }
    }

    // ---- P2: QKV GEMM (B-frags from global wp2, coalesced) -> Q(=tcO region), K, Vt
    {
      s16x8 a0 = *(const s16x8*)&tcO[l15*72 +  0 + l4*8];
      s16x8 a1 = *(const s16x8*)&tcO[l15*72 + 32 + l4*8];
      #pragma unroll
      for (int grp=0; grp<3; ++grp){
        f32x4 acc[4];
        #pragma unroll
        for (int nt=0; nt<4; ++nt){
          s16x8 b0 = *(const s16x8*)&wp2[(((grp*8 + nt*2 + 0)*64 + lane))*8];
          acc[nt] = __builtin_amdgcn_mfma_f32_16x16x32_bf16(a0, b0, z4, 0,0,0);
          s16x8 b1 = *(const s16x8*)&wp2[(((grp*8 + nt*2 + 1)*64 + lane))*8];
          acc[nt] = __builtin_amdgcn_mfma_f32_16x16x32_bf16(a1, b1, acc[nt], 0,0,0);
        }
        #pragma unroll
        for (int nt=0; nt<4; ++nt){
          float bb = in_b[(grp*4+nt)*16 + l15];
          if (grp==0){
            #pragma unroll
            for (int r=0;r<4;++r) tcO[(l4*4 + r)*72 + nt*16 + l15] = bf(acc[nt][r] + bb);  // Q over tcO
          } else if (grp==1){
            #pragma unroll
            for (int r=0;r<4;++r) K[(l4*4 + r)*72 + nt*16 + l15] = bf(acc[nt][r] + bb);
          } else {
            s16x4 pk;
            pk[0]=bf(acc[nt][0]+bb); pk[1]=bf(acc[nt][1]+bb);
            pk[2]=bf(acc[nt][2]+bb); pk[3]=bf(acc[nt][3]+bb);
            *(s16x4*)&Vt[(nt*16 + l15)*16 + l4*4] = pk;
          }
        }
      }
    }

    // ---- P3: attention; O overwrites Q's h-block after that head's reads
    {
      #pragma unroll 1
      for (int h=0; h<4; ++h){
        s16x8 qa = zf, kb = zf;
        if (l4 < 2){
          qa = *(const s16x8*)&tcO[l15*72 + h*16 + l4*8];   // Q
          kb = *(const s16x8*)&K[l15*72 + h*16 + l4*8];
        }
        f32x4 sc = __builtin_amdgcn_mfma_f32_16x16x32_bf16(qa, kb, z4, 0,0,0);  // row=q, col=kt
        float invz[4];
        #pragma unroll
        for (int r=0; r<4; ++r){
          float e = (l15 < 12) ? __expf(sc[r]*0.25f) : 0.f;
          float z = e;
          #pragma unroll
          for (int dd=1; dd<16; dd<<=1) z += __shfl_xor(z, dd);
          invz[r] = 1.f/z;
          Pb[(l4*4 + r)*16 + l15] = bf(e);
        }
        s16x8 pa = zf, vb = zf;
        if (l4 < 2){
          pa = *(const s16x8*)&Pb[l15*16 + l4*8];
          vb = *(const s16x8*)&Vt[(h*16 + l15)*16 + l4*8];
        }
        f32x4 ov = __builtin_amdgcn_mfma_f32_16x16x32_bf16(pa, vb, z4, 0,0,0);  // row=q, col=dh
        #pragma unroll
        for (int r=0; r<4; ++r)
          tcO[(l4*4 + r)*72 + h*16 + l15] = bf(ov[r]*invz[r]);                  // O over Q h-block
      }
    }

    // ---- P4: out-proj (frags from global wp2) + residual + relu + LN -> R[u][o]
    {
      s16x4 zz; zz[0]=0; zz[1]=0; zz[2]=0; zz[3]=0;
      for (int i=lane; i<108; i+=64){
        int rr = i/18, cc = i%18;
        int row = (rr==0) ? 0 : (12 + rr);
        *(s16x4*)&R[row*72 + cc*4] = zz;
      }
      s16x8 a0 = *(const s16x8*)&tcO[l15*72 +  0 + l4*8];
      s16x8 a1 = *(const s16x8*)&tcO[l15*72 + 32 + l4*8];
      f32x4 acc[4];
      #pragma unroll
      for (int nt=0; nt<4; ++nt){
        s16x8 w0 = *(const s16x8*)&wp2[(((24 + nt*2 + 0)*64 + lane))*8];
        acc[nt] = __builtin_amdgcn_mfma_f32_16x16x32_bf16(a0, w0, z4, 0,0,0);
        s16x8 w1 = *(const s16x8*)&wp2[(((24 + nt*2 + 1)*64 + lane))*8];
        acc[nt] = __builtin_amdgcn_mfma_f32_16x16x32_bf16(a1, w1, acc[nt], 0,0,0); // row=t, col=o
      }
      float xr[4];
      #pragma unroll
      for (int r=0; r<4; ++r){ int t=l4*4+r; xr[r] = (t<12) ? x[(size_t)nd*12 + t] : 0.f; }
      float zr[4][4], sum[4]={0,0,0,0}, sq[4]={0,0,0,0};
      #pragma unroll
      for (int nt=0; nt<4; ++nt){
        int o = nt*16 + l15;
        float ob=out_b[o], rw=res_w[o], rb=res_b[o];
        #pragma unroll
        for (int r=0; r<4; ++r){
          float v = acc[nt][r] + ob + xr[r]*rw + rb;
          v = v>0.f ? v : 0.f;
          zr[nt][r]=v; sum[r]+=v; sq[r]+=v*v;
        }
      }
      #pragma unroll
      for (int r=0; r<4; ++r){
        #pragma unroll
        for (int dd=1; dd<16; dd<<=1){ sum[r]+=__shfl_xor(sum[r],dd); sq[r]+=__shfl_xor(sq[r],dd); }
      }
      if (l4 < 3){
        #pragma unroll
        for (int r=0; r<4; ++r){
          float mu = sum[r]*(1.f/64.f);
          float va = sq[r]*(1.f/64.f) - mu*mu;
          float iv = rsqrtf(fmaxf(va,0.f) + 1e-5f);
          #pragma unroll
          for (int nt=0; nt<4; ++nt){
            int o = nt*16 + l15;
            int t = l4*4 + r;
            R[(t + 1)*72 + o] = bf((zr[nt][r]-mu)*iv*ln_g[o] + ln_b[o]);
          }
        }
      }
    }
  }

  __syncthreads();   // drains bc/fc staging DMA

  if (nd < BN){
    // ---- P5+P6 fused: backcast+forecast convs (A = R rows, B = staged lane-major frags)
    f32x4 aB[4] = {z4,z4,z4,z4};
    f32x4 aF[4] = {z4,z4,z4,z4};
    #pragma unroll
    for (int dt=0; dt<3; ++dt){
      #pragma unroll
      for (int kc=0; kc<2; ++kc){
        s16x8 ar = *(const s16x8*)&R[(l15 + dt)*72 + kc*32 + l4*8];
        #pragma unroll
        for (int nt=0; nt<4; ++nt){
          s16x8 wb = *(const s16x8*)&lds[(((dt*8 + kc*4 + nt)*64 + lane))*8];
          aB[nt] = __builtin_amdgcn_mfma_f32_16x16x32_bf16(ar, wb, aB[nt], 0,0,0);
          s16x8 wf = *(const s16x8*)&lds[12288 + (((dt*8 + kc*4 + nt)*64 + lane))*8];
          aF[nt] = __builtin_amdgcn_mfma_f32_16x16x32_bf16(ar, wf, aF[nt], 0,0,0);
        }
      }
    }
    if (l4 < 3){
      #pragma unroll
      for (int nt=0; nt<4; ++nt){
        int o = nt*16 + l15;
        float bb = bc_b[o], fb = fc_b[o];
        float4 v; v.x=aB[nt][0]+bb; v.y=aB[nt][1]+bb; v.z=aB[nt][2]+bb; v.w=aB[nt][3]+bb;
        *(float4*)&out[(size_t)nd*768 + o*12 + l4*4] = v;
        float4 f; f.x=aF[nt][0]+fb; f.y=aF[nt][1]+fb; f.z=aF[nt][2]+fb; f.w=aF[nt][3]+fb;
        *(float4*)&out[30720000 + (size_t)nd*768 + o*12 + l4*4] = f;
      }
    }
  }
}

// ---------------- host ----------------
extern "C" void kernel_launch(void* const* d_in, const int* in_sizes, int n_in,
                              void* d_out, int out_size, void* d_ws, size_t ws_size,
                              hipStream_t stream){
  const float* x      = (const float*)d_in[0];
  const int*   ei     = (const int*)d_in[1];
  const float* cheb_w = (const float*)d_in[2];
  const float* cheb_b = (const float*)d_in[3];
  const float* gat_w  = (const float*)d_in[4];
  const float* att_src= (const float*)d_in[5];
  const float* att_dst= (const float*)d_in[6];
  const float* gat_b  = (const float*)d_in[7];
  const float* tc_w   = (const float*)d_in[8];
  const float* tc_b   = (const float*)d_in[9];
  const float* in_w   = (const float*)d_in[10];
  const float* in_b   = (const float*)d_in[11];
  const float* out_w  = (const float*)d_in[12];
  const float* out_b  = (const float*)d_in[13];
  const float* res_w  = (const float*)d_in[14];
  const float* res_b  = (const float*)d_in[15];
  const float* ln_g   = (const float*)d_in[16];
  const float* ln_b   = (const float*)d_in[17];
  const float* bc_w   = (const float*)d_in[18];
  const float* bc_b   = (const float*)d_in[19];
  const float* fc_w   = (const float*)d_in[20];
  const float* fc_b   = (const float*)d_in[21];
  float* out = (float*)d_out;

  char* w = (char*)d_ws;
  size_t off = 0;
  auto alloc = [&](size_t bytes)->void*{ void* p = w + off; off += (bytes + 255) & ~(size_t)255; return p; };
  int*   cnt2   = (int*)alloc((size_t)2*BN*4);
  int*   degcnt = cnt2;
  int*   cnt    = cnt2 + BN;
  int*   rowptr = (int*)alloc((size_t)(BN+1)*4);
  int*   cursor = (int*)alloc((size_t)BN*4);
  int*   esrc   = (int*)alloc((size_t)EE*4);
  float* ew     = (float*)alloc((size_t)EE*4);
  float* tx1    = (float*)alloc((size_t)BN*TT*4);
  float* tx2    = (float*)alloc((size_t)BN*TT*4);
  float* gwb    = (float*)alloc(1024*4);
  short* wpack  = (short*)alloc((size_t)48640*2);
  short* wpack2 = (short*)alloc((size_t)40960*2);
  float* btc    = (float*)alloc(1024*4);

  size_t coefBytes = (size_t)BN*TT*8*4;
  float* coefp; int cst;
  if (off + coefBytes <= ws_size){ coefp = (float*)(w + off); off += coefBytes; cst = 96; }
  else { coefp = out; cst = 768; }

  hipMemsetAsync(cnt2, 0, (size_t)2*BN*4, stream);
  k_histprep<<<806, 256, 0, stream>>>(ei, degcnt, cnt, cheb_w, cheb_b, gat_w, att_src, att_dst,
                                      gat_b, tc_w, tc_b, in_w, out_w, bc_w, fc_w, gwb, wpack, btc);
  k_scan    <<<1, 1024, 0, stream>>>(cnt, rowptr, cursor);
  k_repack  <<<160, 256, 0, stream>>>(wpack, wpack2);
  k_scatter <<<(EE+255)/256, 256, 0, stream>>>(ei, degcnt, cursor, esrc, ew);
  k_prop1v  <<<(BN*3+255)/256, 256, 0, stream>>>(x, rowptr, esrc, ew, tx1);
  k_prop2v  <<<(BN*3+255)/256, 256, 0, stream>>>(x, tx1, rowptr, esrc, ew, tx2);
  k_gat4    <<<(BN*3+255)/256, 256, 0, stream>>>(x, tx1, tx2, rowptr, esrc, gwb, coefp, cst);
  k_temporal6<<<(BN+13)/14, 896, 0, stream>>>(coefp, cst, x, wpack, wpack2, btc, in_b, out_b,
                                              res_w, res_b, ln_g, ln_b, bc_b, fc_b, out);
}